// Round 1
// baseline (627.580 us; speedup 1.0000x reference)
//
#include <hip/hip_runtime.h>

typedef __attribute__((ext_vector_type(8))) short bf16x8;
typedef __attribute__((ext_vector_type(4))) float f32x4;

#define MFMA16(a,b,c) __builtin_amdgcn_mfma_f32_16x16x32_bf16((a),(b),(c),0,0,0)

__device__ __forceinline__ unsigned short f2bf(float f) {
  unsigned int u = __builtin_bit_cast(unsigned int, f);
  u = (u + 0x7FFFu + ((u >> 16) & 1u)) >> 16;
  return (unsigned short)u;
}

// ---------------- weight transpose fp32 -> bf16, Wt[n][k] = W[k][n] ----------------
__global__ __launch_bounds__(256) void wt_transpose(const float* __restrict__ W,
    unsigned short* __restrict__ Wt)
{
  __shared__ unsigned short T[32][33];
  int kb = blockIdx.x * 32, nb = blockIdx.y * 32;
  int tx = threadIdx.x & 31, ty = threadIdx.x >> 5;
  #pragma unroll
  for (int s = 0; s < 4; ++s)
    T[ty + 8*s][tx] = f2bf(W[(kb + ty + 8*s)*512 + nb + tx]);
  __syncthreads();
  #pragma unroll
  for (int s = 0; s < 4; ++s)
    Wt[(nb + ty + 8*s)*512 + kb + tx] = T[tx][ty + 8*s];
}

// ---------------- V transpose bf16 [4096][512] -> [512][4096] ----------------
__global__ __launch_bounds__(256) void v_transpose(const unsigned short* __restrict__ V,
    unsigned short* __restrict__ Vt)
{
  __shared__ unsigned short T[32][33];
  int mb = blockIdx.x * 32, db = blockIdx.y * 32;
  int tx = threadIdx.x & 31, ty = threadIdx.x >> 5;
  #pragma unroll
  for (int s = 0; s < 4; ++s)
    T[ty + 8*s][tx] = V[(mb + ty + 8*s)*512 + db + tx];
  __syncthreads();
  #pragma unroll
  for (int s = 0; s < 4; ++s)
    Vt[(db + ty + 8*s)*4096 + mb + tx] = T[tx][ty + 8*s];
}

// ---------------- projection GEMM: C[M x 512] = bf16(A) @ W + bias, C bf16 ----------------
// A fp32 row-major, Bt = W^T bf16 (Bt[n][k]), grid (M/128, 8), 256 thr
__global__ __launch_bounds__(256) void proj_gemm(const float* __restrict__ A,
    const unsigned short* __restrict__ Bt, const float* __restrict__ bias,
    unsigned short* __restrict__ C)
{
  __shared__ unsigned short As[128*32];
  __shared__ unsigned short Bs[64*32];
  const int tid = threadIdx.x;
  const int w = tid >> 6, lane = tid & 63;
  const int lr = lane & 15, lg = lane >> 4;
  const int wm = w >> 1, wn = w & 1;
  const int m0 = blockIdx.x * 128, n0 = blockIdx.y * 64;

  f32x4 acc[4][2];
  #pragma unroll
  for (int mt = 0; mt < 4; ++mt)
    #pragma unroll
    for (int nt = 0; nt < 2; ++nt) acc[mt][nt] = (f32x4){0.f,0.f,0.f,0.f};

  const int arow = tid >> 3, af4 = tid & 7;
  const int brow = tid >> 2, bc8 = tid & 3;

  for (int kb = 0; kb < 512; kb += 32) {
    #pragma unroll
    for (int s = 0; s < 4; ++s) {
      const float4 v = *(const float4*)(A + (m0 + arow + 32*s)*512 + kb + af4*4);
      unsigned long long pk = (unsigned long long)f2bf(v.x)
        | ((unsigned long long)f2bf(v.y) << 16)
        | ((unsigned long long)f2bf(v.z) << 32)
        | ((unsigned long long)f2bf(v.w) << 48);
      *(unsigned long long*)&As[(arow + 32*s)*32 + af4*4] = pk;
    }
    *(int4*)&Bs[brow*32 + bc8*8] = *(const int4*)(Bt + (n0 + brow)*512 + kb + bc8*8);
    __syncthreads();
    bf16x8 af[4], bfr[2];
    #pragma unroll
    for (int mt = 0; mt < 4; ++mt)
      af[mt] = *(const bf16x8*)&As[(wm*64 + mt*16 + lr)*32 + lg*8];
    #pragma unroll
    for (int nt = 0; nt < 2; ++nt)
      bfr[nt] = *(const bf16x8*)&Bs[(wn*32 + nt*16 + lr)*32 + lg*8];
    #pragma unroll
    for (int mt = 0; mt < 4; ++mt)
      #pragma unroll
      for (int nt = 0; nt < 2; ++nt)
        acc[mt][nt] = MFMA16(af[mt], bfr[nt], acc[mt][nt]);
    __syncthreads();
  }
  #pragma unroll
  for (int nt = 0; nt < 2; ++nt) {
    int col = n0 + wn*32 + nt*16 + lr;
    float bv = bias[col];
    #pragma unroll
    for (int mt = 0; mt < 4; ++mt) {
      #pragma unroll
      for (int j = 0; j < 4; ++j) {
        int row = m0 + wm*64 + mt*16 + lg*4 + j;
        C[row*512 + col] = f2bf(acc[mt][nt][j] + bv);
      }
    }
  }
}

// ---------------- flash attention: out = x + softmax(q k^T s) v ----------------
// grid 512 (16 q-rows each), 256 thr (4 waves). K, Vt read direct from global (L2/L3-fit).
__global__ __launch_bounds__(256) void attn_kernel(
    const unsigned short* __restrict__ q,   // [8192][512] bf16
    const unsigned short* __restrict__ mk,  // [4096][512] bf16
    const unsigned short* __restrict__ vt,  // [512][4096] bf16
    const float* __restrict__ x,            // [8192][512]
    float* __restrict__ out)                // [8192][512]
{
  __shared__ float m_lds[16], l_lds[16];
  __shared__ float redmax[4][16], redsum[4][16];
  __shared__ unsigned short Ps[16*64];   // XOR-swizzled

  const int tid = threadIdx.x;
  const int w = tid >> 6, lane = tid & 63;
  const int lr = lane & 15, lg = lane >> 4;
  const int q0 = blockIdx.x * 16;
  const int cbase = w * 16;    // this wave's S columns (kv tile offset)
  const int dbase = w * 128;   // this wave's output d-slice

  if (tid < 16) { m_lds[tid] = -1e30f; l_lds[tid] = 0.0f; }

  bf16x8 qa[16];
  {
    const bf16x8* qp = (const bf16x8*)(q + (q0 + lr) * 512);
    #pragma unroll
    for (int ks = 0; ks < 16; ++ks) qa[ks] = qp[ks*4 + lg];
  }
  f32x4 o[8];
  #pragma unroll
  for (int nt = 0; nt < 8; ++nt) o[nt] = (f32x4){0.f,0.f,0.f,0.f};

  __syncthreads();

  const float scale = 0.04419417382415922f;  // 512^-0.5

  for (int kv0 = 0; kv0 < 4096; kv0 += 64) {
    // QK^T: S[16 x 16] per wave (cols cbase..cbase+15)
    f32x4 s = (f32x4){0.f,0.f,0.f,0.f};
    const unsigned short* kr = mk + (kv0 + cbase + lr) * 512 + lg * 8;
    #pragma unroll
    for (int ks = 0; ks < 16; ++ks) {
      bf16x8 kb = *(const bf16x8*)(kr + ks * 32);
      s = MFMA16(qa[ks], kb, s);
    }
    #pragma unroll
    for (int j = 0; j < 4; ++j) s[j] *= scale;

    // wave-local row max over 16 cols (lanes with same lg)
    f32x4 rm = s;
    #pragma unroll
    for (int m = 1; m < 16; m <<= 1) {
      #pragma unroll
      for (int j = 0; j < 4; ++j) rm[j] = fmaxf(rm[j], __shfl_xor(rm[j], m));
    }
    if (lr == 0) {
      #pragma unroll
      for (int j = 0; j < 4; ++j) redmax[w][lg*4 + j] = rm[j];
    }
    __syncthreads();  // B1

    float f[4], p[4];
    #pragma unroll
    for (int j = 0; j < 4; ++j) {
      int r = lg*4 + j;
      float tmax = fmaxf(fmaxf(redmax[0][r], redmax[1][r]),
                         fmaxf(redmax[2][r], redmax[3][r]));
      float mo = m_lds[r];
      float mn = fmaxf(mo, tmax);
      f[j] = __expf(mo - mn);
      p[j] = __expf(s[j] - mn);
      int idx = (r*64 + cbase + lr) ^ ((r & 7) << 3);
      Ps[idx] = f2bf(p[j]);
    }
    f32x4 rs;
    #pragma unroll
    for (int j = 0; j < 4; ++j) rs[j] = p[j];
    #pragma unroll
    for (int m = 1; m < 16; m <<= 1) {
      #pragma unroll
      for (int j = 0; j < 4; ++j) rs[j] += __shfl_xor(rs[j], m);
    }
    if (lr == 0) {
      #pragma unroll
      for (int j = 0; j < 4; ++j) redsum[w][lg*4 + j] = rs[j];
    }
    #pragma unroll
    for (int nt = 0; nt < 8; ++nt)
      #pragma unroll
      for (int j = 0; j < 4; ++j) o[nt][j] *= f[j];
    __syncthreads();  // B2

    if (tid < 16) {
      int r = tid;
      float tmax = fmaxf(fmaxf(redmax[0][r], redmax[1][r]),
                         fmaxf(redmax[2][r], redmax[3][r]));
      float mo = m_lds[r];
      float mn = fmaxf(mo, tmax);
      float ff = __expf(mo - mn);
      l_lds[r] = l_lds[r] * ff + (redsum[0][r] + redsum[1][r] + redsum[2][r] + redsum[3][r]);
      m_lds[r] = mn;
    }
    __syncthreads();  // B3

    // PV: o += P[16 x 64] @ V[64 x 128-slice]
    bf16x8 pa[2];
    #pragma unroll
    for (int ks2 = 0; ks2 < 2; ++ks2) {
      int boff = (lr*128 + ks2*64 + lg*16) ^ ((lr & 7) << 4);
      pa[ks2] = *(const bf16x8*)((const char*)Ps + boff);
    }
    const unsigned short* vb0 = vt + (dbase + lr) * 4096 + kv0 + lg * 8;
    #pragma unroll
    for (int nt = 0; nt < 8; ++nt) {
      const unsigned short* vr = vb0 + nt * 16 * 4096;
      #pragma unroll
      for (int ks2 = 0; ks2 < 2; ++ks2) {
        bf16x8 vb = *(const bf16x8*)(vr + ks2 * 32);
        o[nt] = MFMA16(pa[ks2], vb, o[nt]);
      }
    }
  }

  #pragma unroll
  for (int nt = 0; nt < 8; ++nt) {
    int col = dbase + nt*16 + lr;
    #pragma unroll
    for (int j = 0; j < 4; ++j) {
      int r = lg*4 + j;
      int row = q0 + r;
      float val = o[nt][j] / l_lds[r];
      out[row*512 + col] = x[row*512 + col] + val;
    }
  }
}

// ---------------- recon path (fp32 exact) ----------------
__global__ __launch_bounds__(256) void compress_pool(const float* __restrict__ fine,
    const float* __restrict__ cq, float* __restrict__ pooled)
{
  int l = blockIdx.x;
  int t = threadIdx.x;
  const float* c0 = fine + (2*l)*512;
  const float* c1 = c0 + 512;
  float q0 = cq[t], q1 = cq[t+256];
  float a0 = q0*c0[t] + q1*c0[t+256];
  float a1 = q0*c1[t] + q1*c1[t+256];
  #pragma unroll
  for (int m = 1; m < 64; m <<= 1) { a0 += __shfl_xor(a0, m); a1 += __shfl_xor(a1, m); }
  __shared__ float r0[4], r1[4];
  int w = t >> 6;
  if ((t & 63) == 0) { r0[w] = a0; r1[w] = a1; }
  __syncthreads();
  const float sc = 0.04419417382415922f;
  float g0 = (r0[0]+r0[1]+r0[2]+r0[3]) * sc;
  float g1 = (r1[0]+r1[1]+r1[2]+r1[3]) * sc;
  float mx = fmaxf(g0, g1);
  float e0 = __expf(g0-mx), e1 = __expf(g1-mx);
  float inv = 1.0f/(e0+e1);
  float w0 = e0*inv, w1 = e1*inv;
  pooled[l*512 + t]       = w0*c0[t]     + w1*c1[t];
  pooled[l*512 + t + 256] = w0*c0[t+256] + w1*c1[t+256];
}

__global__ __launch_bounds__(256) void comp_gemm(const float* __restrict__ P,
    const float* __restrict__ W, const float* __restrict__ b, float* __restrict__ out)
{
  int gid = blockIdx.x * 256 + threadIdx.x;
  int m = gid >> 9, n = gid & 511;
  const float* a = P + m * 512;
  float acc = b[n];
  #pragma unroll 8
  for (int k = 0; k < 512; ++k) acc += a[k] * W[k*512 + n];
  out[gid] = acc;
}

__global__ void zero_one(float* p) { *p = 0.f; }

__global__ __launch_bounds__(256) void interp_loss(const float* __restrict__ comp,
    const float* __restrict__ fine, float* __restrict__ loss)
{
  float acc = 0.f;
  #pragma unroll
  for (int s = 0; s < 4; ++s) {
    int e = blockIdx.x*1024 + s*256 + threadIdx.x;
    int i = e >> 9, d = e & 511;
    float src = fminf(fmaxf((i + 0.5f)*0.5f - 0.5f, 0.f), 255.f);
    int i0 = (int)src;
    int i1 = min(i0 + 1, 255);
    float fr = src - (float)i0;
    float dec = (1.f - fr)*comp[i0*512 + d] + fr*comp[i1*512 + d];
    float df = dec - fine[e];
    acc += df*df;
  }
  #pragma unroll
  for (int m = 1; m < 64; m <<= 1) acc += __shfl_xor(acc, m);
  __shared__ float r[4];
  int w = threadIdx.x >> 6;
  if ((threadIdx.x & 63) == 0) r[w] = acc;
  __syncthreads();
  if (threadIdx.x == 0)
    atomicAdd(loss, (r[0]+r[1]+r[2]+r[3]) * (1.0f/262144.0f));
}

extern "C" void kernel_launch(void* const* d_in, const int* in_sizes, int n_in,
                              void* d_out, int out_size, void* d_ws, size_t ws_size,
                              hipStream_t stream) {
  const float* x     = (const float*)d_in[0];
  const float* fine  = (const float*)d_in[1];
  const float* cmem  = (const float*)d_in[2];
  const float* cq    = (const float*)d_in[3];
  const float* compW = (const float*)d_in[4];
  const float* compb = (const float*)d_in[5];
  const float* kW    = (const float*)d_in[6];
  const float* kb_   = (const float*)d_in[7];
  const float* vW    = (const float*)d_in[8];
  const float* vb_   = (const float*)d_in[9];
  const float* xkW   = (const float*)d_in[10];
  const float* xkb   = (const float*)d_in[11];
  const float* ckW   = (const float*)d_in[12];
  const float* ckb   = (const float*)d_in[13];
  const float* cvW   = (const float*)d_in[14];
  const float* cvb   = (const float*)d_in[15];

  char* ws = (char*)d_ws;
  const size_t WT = 512*512*2;              // 512 KB per transposed weight
  unsigned short* WtK  = (unsigned short*)(ws + 0*WT);
  unsigned short* WtV  = (unsigned short*)(ws + 1*WT);
  unsigned short* WtCK = (unsigned short*)(ws + 2*WT);
  unsigned short* WtCV = (unsigned short*)(ws + 3*WT);
  unsigned short* WtXK = (unsigned short*)(ws + 4*WT);
  char* base = ws + 5*WT;
  unsigned short* memk = (unsigned short*)(base);                       // 4 MB
  unsigned short* memv = (unsigned short*)(base + (4u<<20));            // 4 MB
  unsigned short* vt   = (unsigned short*)(base + (8u<<20));            // 4 MB
  unsigned short* qry  = (unsigned short*)(base + (12u<<20));           // 8 MB
  float* pooled        = (float*)(base + (20u<<20));                    // 512 KB
  float* comp          = (float*)(base + (20u<<20) + (512u<<10));       // 512 KB

  float* out  = (float*)d_out;
  float* loss = out + 8192*512;

  dim3 tgrid(16,16);
  wt_transpose<<<tgrid, 256, 0, stream>>>(kW,  WtK);
  wt_transpose<<<tgrid, 256, 0, stream>>>(vW,  WtV);
  wt_transpose<<<tgrid, 256, 0, stream>>>(ckW, WtCK);
  wt_transpose<<<tgrid, 256, 0, stream>>>(cvW, WtCV);
  wt_transpose<<<tgrid, 256, 0, stream>>>(xkW, WtXK);

  proj_gemm<<<dim3(16,8), 256, 0, stream>>>(fine, WtK,  kb_, memk);
  proj_gemm<<<dim3(16,8), 256, 0, stream>>>(cmem, WtCK, ckb, memk + 2048*512);
  proj_gemm<<<dim3(16,8), 256, 0, stream>>>(fine, WtV,  vb_, memv);
  proj_gemm<<<dim3(16,8), 256, 0, stream>>>(cmem, WtCV, cvb, memv + 2048*512);
  proj_gemm<<<dim3(64,8), 256, 0, stream>>>(x,    WtXK, xkb, qry);

  v_transpose<<<dim3(128,16), 256, 0, stream>>>(memv, vt);

  attn_kernel<<<512, 256, 0, stream>>>(qry, memk, vt, x, out);

  compress_pool<<<256, 256, 0, stream>>>(fine, cq, pooled);
  comp_gemm<<<512, 256, 0, stream>>>(pooled, compW, compb, comp);
  zero_one<<<1, 1, 0, stream>>>(loss);
  interp_loss<<<256, 256, 0, stream>>>(comp, fine, loss);
}

// Round 2
// 314.647 us; speedup vs baseline: 1.9946x; 1.9946x over previous
//
#include <hip/hip_runtime.h>

typedef __attribute__((ext_vector_type(8))) short bf16x8;
typedef __attribute__((ext_vector_type(4))) float f32x4;

#define MFMA16(a,b,c) __builtin_amdgcn_mfma_f32_16x16x32_bf16((a),(b),(c),0,0,0)

__device__ __forceinline__ unsigned short f2bf(float f) {
  unsigned int u = __builtin_bit_cast(unsigned int, f);
  u = (u + 0x7FFFu + ((u >> 16) & 1u)) >> 16;
  return (unsigned short)u;
}
__device__ __forceinline__ float bf2f(unsigned short u) {
  unsigned int v = ((unsigned int)u) << 16;
  return __builtin_bit_cast(float, v);
}

// ---------------- weight transpose fp32 -> bf16, Wt[n][k] = W[k][n] ----------------
__global__ __launch_bounds__(256) void wt_transpose(const float* __restrict__ W,
    unsigned short* __restrict__ Wt)
{
  __shared__ unsigned short T[32][33];
  int kb = blockIdx.x * 32, nb = blockIdx.y * 32;
  int tx = threadIdx.x & 31, ty = threadIdx.x >> 5;
  #pragma unroll
  for (int s = 0; s < 4; ++s)
    T[ty + 8*s][tx] = f2bf(W[(kb + ty + 8*s)*512 + nb + tx]);
  __syncthreads();
  #pragma unroll
  for (int s = 0; s < 4; ++s)
    Wt[(nb + ty + 8*s)*512 + kb + tx] = T[tx][ty + 8*s];
}

// ---------------- V transpose bf16 [4096][512] -> [512][4096] ----------------
__global__ __launch_bounds__(256) void v_transpose(const unsigned short* __restrict__ V,
    unsigned short* __restrict__ Vt)
{
  __shared__ unsigned short T[32][33];
  int mb = blockIdx.x * 32, db = blockIdx.y * 32;
  int tx = threadIdx.x & 31, ty = threadIdx.x >> 5;
  #pragma unroll
  for (int s = 0; s < 4; ++s)
    T[ty + 8*s][tx] = V[(mb + ty + 8*s)*512 + db + tx];
  __syncthreads();
  #pragma unroll
  for (int s = 0; s < 4; ++s)
    Vt[(db + ty + 8*s)*4096 + mb + tx] = T[tx][ty + 8*s];
}

// ---------------- projection GEMM: C[M x 512] = bf16(A) @ W + bias, C bf16 ----------------
__global__ __launch_bounds__(256) void proj_gemm(const float* __restrict__ A,
    const unsigned short* __restrict__ Bt, const float* __restrict__ bias,
    unsigned short* __restrict__ C)
{
  __shared__ unsigned short As[128*32];
  __shared__ unsigned short Bs[64*32];
  const int tid = threadIdx.x;
  const int w = tid >> 6, lane = tid & 63;
  const int lr = lane & 15, lg = lane >> 4;
  const int wm = w >> 1, wn = w & 1;
  const int m0 = blockIdx.x * 128, n0 = blockIdx.y * 64;

  f32x4 acc[4][2];
  #pragma unroll
  for (int mt = 0; mt < 4; ++mt)
    #pragma unroll
    for (int nt = 0; nt < 2; ++nt) acc[mt][nt] = (f32x4){0.f,0.f,0.f,0.f};

  const int arow = tid >> 3, af4 = tid & 7;
  const int brow = tid >> 2, bc8 = tid & 3;

  for (int kb = 0; kb < 512; kb += 32) {
    #pragma unroll
    for (int s = 0; s < 4; ++s) {
      const float4 v = *(const float4*)(A + (m0 + arow + 32*s)*512 + kb + af4*4);
      unsigned long long pk = (unsigned long long)f2bf(v.x)
        | ((unsigned long long)f2bf(v.y) << 16)
        | ((unsigned long long)f2bf(v.z) << 32)
        | ((unsigned long long)f2bf(v.w) << 48);
      *(unsigned long long*)&As[(arow + 32*s)*32 + af4*4] = pk;
    }
    *(int4*)&Bs[brow*32 + bc8*8] = *(const int4*)(Bt + (n0 + brow)*512 + kb + bc8*8);
    __syncthreads();
    bf16x8 af[4], bfr[2];
    #pragma unroll
    for (int mt = 0; mt < 4; ++mt)
      af[mt] = *(const bf16x8*)&As[(wm*64 + mt*16 + lr)*32 + lg*8];
    #pragma unroll
    for (int nt = 0; nt < 2; ++nt)
      bfr[nt] = *(const bf16x8*)&Bs[(wn*32 + nt*16 + lr)*32 + lg*8];
    #pragma unroll
    for (int mt = 0; mt < 4; ++mt)
      #pragma unroll
      for (int nt = 0; nt < 2; ++nt)
        acc[mt][nt] = MFMA16(af[mt], bfr[nt], acc[mt][nt]);
    __syncthreads();
  }
  #pragma unroll
  for (int nt = 0; nt < 2; ++nt) {
    int col = n0 + wn*32 + nt*16 + lr;
    float bv = bias[col];
    #pragma unroll
    for (int mt = 0; mt < 4; ++mt) {
      #pragma unroll
      for (int j = 0; j < 4; ++j) {
        int row = m0 + wm*64 + mt*16 + lg*4 + j;
        C[row*512 + col] = f2bf(acc[mt][nt][j] + bv);
      }
    }
  }
}

// ---------------- flash attention partials ----------------
// grid 512 = 128 q-blocks x 4 kv-chunks (chunk = bid&3 -> XCD-affine).
// Block: 4 waves; wave w owns q rows q0..q0+15, full d=512.
// Per iter: stage K[32][512] (global_load_lds) + Vt[512][32] (reg) into LDS; 2 barriers.
__global__ __launch_bounds__(256, 2) void attn_kernel(
    const unsigned short* __restrict__ q,   // [8192][512] bf16
    const unsigned short* __restrict__ mk,  // [4096][512] bf16
    const unsigned short* __restrict__ vt,  // [512][4096] bf16
    unsigned short* __restrict__ opart,     // [4][8192][512] bf16, unnormalized
    float* __restrict__ mpart,              // [4][8192]
    float* __restrict__ lpart)              // [4][8192]
{
  __shared__ unsigned short Ks[32*520];     // rows padded to 520 elems (1040 B)
  __shared__ unsigned short Vst[512*40];    // rows padded to 40 elems (80 B)
  __shared__ unsigned short Pb[4][16*40];   // per-wave P, rows padded to 40

  const int tid = threadIdx.x;
  const int w = tid >> 6, lane = tid & 63;
  const int lr = lane & 15, lg = lane >> 4;
  const int bid = blockIdx.x;
  const int chunk = bid & 3;
  const int qb = bid >> 2;
  const int q0 = qb * 64 + w * 16;
  const int kvbase = chunk * 1024;
  const float scale = 0.04419417382415922f;  // 512^-0.5

  // Q fragments: qa[ks] covers k = ks*32 + lg*8 .. +8 for row q0+lr
  bf16x8 qa[16];
  {
    const bf16x8* qp = (const bf16x8*)(q + (q0 + lr) * 512);
    #pragma unroll
    for (int ks = 0; ks < 16; ++ks) qa[ks] = qp[ks*4 + lg];
  }
  f32x4 o[32];
  #pragma unroll
  for (int nt = 0; nt < 32; ++nt) o[nt] = (f32x4){0.f,0.f,0.f,0.f};
  float m[4] = {-1e30f,-1e30f,-1e30f,-1e30f};
  float l[4] = {0.f,0.f,0.f,0.f};

  const int vrow = tid >> 2, vcol = (tid & 3) * 8;

  for (int it = 0; it < 32; ++it) {
    const int kv0 = kvbase + it * 32;
    // ---- stage K: 8 rows per wave, direct global->LDS (no VGPR) ----
    #pragma unroll
    for (int i = 0; i < 8; ++i) {
      int r = w * 8 + i;
      __builtin_amdgcn_global_load_lds(
        (const __attribute__((address_space(1))) unsigned int*)(mk + (kv0 + r)*512 + lane*8),
        (__attribute__((address_space(3))) unsigned int*)(&Ks[r*520]), 16, 0, 0);
    }
    // ---- stage Vt columns kv0..kv0+31 -> Vst[512][40] (reg-staged, 2x4 batches) ----
    #pragma unroll
    for (int p2 = 0; p2 < 2; ++p2) {
      int4 va[4];
      #pragma unroll
      for (int pp = 0; pp < 4; ++pp) {
        int d = (p2*4 + pp)*64 + vrow;
        va[pp] = *(const int4*)(vt + d*4096 + kv0 + vcol);
      }
      #pragma unroll
      for (int pp = 0; pp < 4; ++pp) {
        int d = (p2*4 + pp)*64 + vrow;
        *(int4*)&Vst[d*40 + vcol] = va[pp];
      }
    }
    __syncthreads();

    // ---- QK^T: S[16 x 32] per wave ----
    f32x4 s0 = (f32x4){0.f,0.f,0.f,0.f}, s1 = (f32x4){0.f,0.f,0.f,0.f};
    #pragma unroll
    for (int ks = 0; ks < 16; ++ks) {
      bf16x8 kb0 = *(const bf16x8*)&Ks[lr*520 + ks*32 + lg*8];
      bf16x8 kb1 = *(const bf16x8*)&Ks[(lr + 16)*520 + ks*32 + lg*8];
      s0 = MFMA16(qa[ks], kb0, s0);
      s1 = MFMA16(qa[ks], kb1, s1);
    }
    float pm[4];
    #pragma unroll
    for (int j = 0; j < 4; ++j) {
      s0[j] *= scale; s1[j] *= scale;
      pm[j] = fmaxf(s0[j], s1[j]);
    }
    #pragma unroll
    for (int msk = 1; msk < 16; msk <<= 1)
      #pragma unroll
      for (int j = 0; j < 4; ++j) pm[j] = fmaxf(pm[j], __shfl_xor(pm[j], msk));

    bool ok = (pm[0] <= m[0] + 8.f) && (pm[1] <= m[1] + 8.f)
           && (pm[2] <= m[2] + 8.f) && (pm[3] <= m[3] + 8.f);
    if (!__all(ok)) {
      #pragma unroll
      for (int j = 0; j < 4; ++j) {
        float mn = fmaxf(m[j], pm[j]);
        float f = __expf(m[j] - mn);
        l[j] *= f;
        m[j] = mn;
        #pragma unroll
        for (int nt = 0; nt < 32; ++nt) o[nt][j] *= f;
      }
    }
    float rs[4];
    #pragma unroll
    for (int j = 0; j < 4; ++j) {
      float p0 = __expf(s0[j] - m[j]);
      float p1 = __expf(s1[j] - m[j]);
      rs[j] = p0 + p1;
      Pb[w][(lg*4 + j)*40 + lr] = f2bf(p0);
      Pb[w][(lg*4 + j)*40 + 16 + lr] = f2bf(p1);
    }
    #pragma unroll
    for (int msk = 1; msk < 16; msk <<= 1)
      #pragma unroll
      for (int j = 0; j < 4; ++j) rs[j] += __shfl_xor(rs[j], msk);
    #pragma unroll
    for (int j = 0; j < 4; ++j) l[j] += rs[j];

    // ---- PV: O[16 x 512] += P[16 x 32] @ V[32 x 512] ----
    bf16x8 pa = *(const bf16x8*)&Pb[w][lr*40 + lg*8];
    #pragma unroll
    for (int nt = 0; nt < 32; ++nt) {
      bf16x8 vb = *(const bf16x8*)&Vst[(nt*16 + lr)*40 + lg*8];
      o[nt] = MFMA16(pa, vb, o[nt]);
    }
    __syncthreads();
  }

  // ---- store unnormalized partial + m/l ----
  unsigned short* ob = opart + (size_t)chunk * 8192 * 512;
  #pragma unroll
  for (int nt = 0; nt < 32; ++nt) {
    #pragma unroll
    for (int j = 0; j < 4; ++j) {
      int row = q0 + lg*4 + j;
      ob[row*512 + nt*16 + lr] = f2bf(o[nt][j]);
    }
  }
  if (lr == 0) {
    #pragma unroll
    for (int j = 0; j < 4; ++j) {
      int row = q0 + lg*4 + j;
      mpart[chunk*8192 + row] = m[j];
      lpart[chunk*8192 + row] = l[j];
    }
  }
}

// ---------------- combine partials: out = x + (sum_c w_c O~_c) / (sum_c w_c l_c) ----------------
__global__ __launch_bounds__(256) void attn_combine(
    const unsigned short* __restrict__ opart, const float* __restrict__ mpart,
    const float* __restrict__ lpart, const float* __restrict__ x,
    float* __restrict__ out)
{
  int row = blockIdx.x * 2 + (threadIdx.x >> 7);
  int t = threadIdx.x & 127;
  int d0 = t * 4;
  float mc[4], lc[4];
  #pragma unroll
  for (int c = 0; c < 4; ++c) { mc[c] = mpart[c*8192 + row]; lc[c] = lpart[c*8192 + row]; }
  float M = fmaxf(fmaxf(mc[0], mc[1]), fmaxf(mc[2], mc[3]));
  float wc[4], denom = 0.f;
  #pragma unroll
  for (int c = 0; c < 4; ++c) { wc[c] = __expf(mc[c] - M); denom += wc[c] * lc[c]; }
  float inv = 1.0f / denom;
  float acc[4] = {0.f, 0.f, 0.f, 0.f};
  const unsigned short* base = opart + row*512 + d0;
  #pragma unroll
  for (int c = 0; c < 4; ++c) {
    ushort4 v = *(const ushort4*)(base + (size_t)c * 8192 * 512);
    acc[0] += wc[c]*bf2f(v.x); acc[1] += wc[c]*bf2f(v.y);
    acc[2] += wc[c]*bf2f(v.z); acc[3] += wc[c]*bf2f(v.w);
  }
  float4 xv = *(const float4*)(x + row*512 + d0);
  float4 ov;
  ov.x = xv.x + acc[0]*inv; ov.y = xv.y + acc[1]*inv;
  ov.z = xv.z + acc[2]*inv; ov.w = xv.w + acc[3]*inv;
  *(float4*)(out + row*512 + d0) = ov;
}

// ---------------- recon path (fp32 exact) ----------------
__global__ __launch_bounds__(256) void compress_pool(const float* __restrict__ fine,
    const float* __restrict__ cq, float* __restrict__ pooled)
{
  int l = blockIdx.x;
  int t = threadIdx.x;
  const float* c0 = fine + (2*l)*512;
  const float* c1 = c0 + 512;
  float q0 = cq[t], q1 = cq[t+256];
  float a0 = q0*c0[t] + q1*c0[t+256];
  float a1 = q0*c1[t] + q1*c1[t+256];
  #pragma unroll
  for (int m = 1; m < 64; m <<= 1) { a0 += __shfl_xor(a0, m); a1 += __shfl_xor(a1, m); }
  __shared__ float r0[4], r1[4];
  int w = t >> 6;
  if ((t & 63) == 0) { r0[w] = a0; r1[w] = a1; }
  __syncthreads();
  const float sc = 0.04419417382415922f;
  float g0 = (r0[0]+r0[1]+r0[2]+r0[3]) * sc;
  float g1 = (r1[0]+r1[1]+r1[2]+r1[3]) * sc;
  float mx = fmaxf(g0, g1);
  float e0 = __expf(g0-mx), e1 = __expf(g1-mx);
  float inv = 1.0f/(e0+e1);
  float w0 = e0*inv, w1 = e1*inv;
  pooled[l*512 + t]       = w0*c0[t]     + w1*c1[t];
  pooled[l*512 + t + 256] = w0*c0[t+256] + w1*c1[t+256];
}

__global__ __launch_bounds__(256) void comp_gemm(const float* __restrict__ P,
    const float* __restrict__ W, const float* __restrict__ b, float* __restrict__ out)
{
  int gid = blockIdx.x * 256 + threadIdx.x;
  int m = gid >> 9, n = gid & 511;
  const float* a = P + m * 512;
  float acc = b[n];
  #pragma unroll 8
  for (int k = 0; k < 512; ++k) acc += a[k] * W[k*512 + n];
  out[gid] = acc;
}

__global__ void zero_one(float* p) { *p = 0.f; }

__global__ __launch_bounds__(256) void interp_loss(const float* __restrict__ comp,
    const float* __restrict__ fine, float* __restrict__ loss)
{
  float acc = 0.f;
  #pragma unroll
  for (int s = 0; s < 4; ++s) {
    int e = blockIdx.x*1024 + s*256 + threadIdx.x;
    int i = e >> 9, d = e & 511;
    float src = fminf(fmaxf((i + 0.5f)*0.5f - 0.5f, 0.f), 255.f);
    int i0 = (int)src;
    int i1 = min(i0 + 1, 255);
    float fr = src - (float)i0;
    float dec = (1.f - fr)*comp[i0*512 + d] + fr*comp[i1*512 + d];
    float df = dec - fine[e];
    acc += df*df;
  }
  #pragma unroll
  for (int m = 1; m < 64; m <<= 1) acc += __shfl_xor(acc, m);
  __shared__ float r[4];
  int w = threadIdx.x >> 6;
  if ((threadIdx.x & 63) == 0) r[w] = acc;
  __syncthreads();
  if (threadIdx.x == 0)
    atomicAdd(loss, (r[0]+r[1]+r[2]+r[3]) * (1.0f/262144.0f));
}

extern "C" void kernel_launch(void* const* d_in, const int* in_sizes, int n_in,
                              void* d_out, int out_size, void* d_ws, size_t ws_size,
                              hipStream_t stream) {
  const float* x     = (const float*)d_in[0];
  const float* fine  = (const float*)d_in[1];
  const float* cmem  = (const float*)d_in[2];
  const float* cq    = (const float*)d_in[3];
  const float* compW = (const float*)d_in[4];
  const float* compb = (const float*)d_in[5];
  const float* kW    = (const float*)d_in[6];
  const float* kb_   = (const float*)d_in[7];
  const float* vW    = (const float*)d_in[8];
  const float* vb_   = (const float*)d_in[9];
  const float* xkW   = (const float*)d_in[10];
  const float* xkb   = (const float*)d_in[11];
  const float* ckW   = (const float*)d_in[12];
  const float* ckb   = (const float*)d_in[13];
  const float* cvW   = (const float*)d_in[14];
  const float* cvb   = (const float*)d_in[15];

  char* ws = (char*)d_ws;
  const size_t WT = 512*512*2;              // 512 KB per transposed weight
  unsigned short* WtK  = (unsigned short*)(ws + 0*WT);
  unsigned short* WtV  = (unsigned short*)(ws + 1*WT);
  unsigned short* WtCK = (unsigned short*)(ws + 2*WT);
  unsigned short* WtCV = (unsigned short*)(ws + 3*WT);
  unsigned short* WtXK = (unsigned short*)(ws + 4*WT);
  char* base = ws + 5*WT;
  unsigned short* memk = (unsigned short*)(base);                       // 4 MB
  unsigned short* memv = (unsigned short*)(base + (4u<<20));            // 4 MB
  unsigned short* vt   = (unsigned short*)(base + (8u<<20));            // 4 MB
  unsigned short* qry  = (unsigned short*)(base + (12u<<20));           // 8 MB
  float* pooled        = (float*)(base + (20u<<20));                    // 512 KB
  float* comp          = (float*)(base + (20u<<20) + (512u<<10));       // 512 KB
  unsigned short* opart= (unsigned short*)(base + (21u<<20));           // 32 MB
  float* mpart         = (float*)(base + (53u<<20));                    // 128 KB
  float* lpart         = (float*)(base + (53u<<20) + (128u<<10));      // 128 KB

  float* out  = (float*)d_out;
  float* loss = out + 8192*512;

  dim3 tgrid(16,16);
  wt_transpose<<<tgrid, 256, 0, stream>>>(kW,  WtK);
  wt_transpose<<<tgrid, 256, 0, stream>>>(vW,  WtV);
  wt_transpose<<<tgrid, 256, 0, stream>>>(ckW, WtCK);
  wt_transpose<<<tgrid, 256, 0, stream>>>(cvW, WtCV);
  wt_transpose<<<tgrid, 256, 0, stream>>>(xkW, WtXK);

  proj_gemm<<<dim3(16,8), 256, 0, stream>>>(fine, WtK,  kb_, memk);
  proj_gemm<<<dim3(16,8), 256, 0, stream>>>(cmem, WtCK, ckb, memk + 2048*512);
  proj_gemm<<<dim3(16,8), 256, 0, stream>>>(fine, WtV,  vb_, memv);
  proj_gemm<<<dim3(16,8), 256, 0, stream>>>(cmem, WtCV, cvb, memv + 2048*512);
  proj_gemm<<<dim3(64,8), 256, 0, stream>>>(x,    WtXK, xkb, qry);

  v_transpose<<<dim3(128,16), 256, 0, stream>>>(memv, vt);

  attn_kernel<<<512, 256, 0, stream>>>(qry, memk, vt, opart, mpart, lpart);
  attn_combine<<<4096, 256, 0, stream>>>(opart, mpart, lpart, x, out);

  compress_pool<<<256, 256, 0, stream>>>(fine, cq, pooled);
  comp_gemm<<<512, 256, 0, stream>>>(pooled, compW, compb, comp);
  zero_one<<<1, 1, 0, stream>>>(loss);
  interp_loss<<<256, 256, 0, stream>>>(comp, fine, loss);
}

// Round 3
// 289.744 us; speedup vs baseline: 2.1660x; 1.0859x over previous
//
#include <hip/hip_runtime.h>

typedef __attribute__((ext_vector_type(8))) short bf16x8;
typedef __attribute__((ext_vector_type(4))) float f32x4;

#define MFMA16(a,b,c) __builtin_amdgcn_mfma_f32_16x16x32_bf16((a),(b),(c),0,0,0)

__device__ __forceinline__ unsigned short f2bf(float f) {
  unsigned int u = __builtin_bit_cast(unsigned int, f);
  u = (u + 0x7FFFu + ((u >> 16) & 1u)) >> 16;
  return (unsigned short)u;
}
__device__ __forceinline__ float bf2f(unsigned short u) {
  unsigned int v = ((unsigned int)u) << 16;
  return __builtin_bit_cast(float, v);
}

// ---------------- fused weight transpose fp32 -> bf16, Wt[n][k] = W[k][n], z selects ----------------
__global__ __launch_bounds__(256) void wt_transpose5(
    const float* __restrict__ W0, const float* __restrict__ W1,
    const float* __restrict__ W2, const float* __restrict__ W3,
    const float* __restrict__ W4,
    unsigned short* __restrict__ O0, unsigned short* __restrict__ O1,
    unsigned short* __restrict__ O2, unsigned short* __restrict__ O3,
    unsigned short* __restrict__ O4)
{
  const float* W; unsigned short* Wt;
  switch (blockIdx.z) {
    case 0: W = W0; Wt = O0; break;
    case 1: W = W1; Wt = O1; break;
    case 2: W = W2; Wt = O2; break;
    case 3: W = W3; Wt = O3; break;
    default: W = W4; Wt = O4; break;
  }
  __shared__ unsigned short T[32][33];
  int kb = blockIdx.x * 32, nb = blockIdx.y * 32;
  int tx = threadIdx.x & 31, ty = threadIdx.x >> 5;
  #pragma unroll
  for (int s = 0; s < 4; ++s)
    T[ty + 8*s][tx] = f2bf(W[(kb + ty + 8*s)*512 + nb + tx]);
  __syncthreads();
  #pragma unroll
  for (int s = 0; s < 4; ++s)
    Wt[(nb + ty + 8*s)*512 + kb + tx] = T[tx][ty + 8*s];
}

// ---------------- V transpose bf16 [4096][512] -> [512][4096] ----------------
__global__ __launch_bounds__(256) void v_transpose(const unsigned short* __restrict__ V,
    unsigned short* __restrict__ Vt)
{
  __shared__ unsigned short T[32][33];
  int mb = blockIdx.x * 32, db = blockIdx.y * 32;
  int tx = threadIdx.x & 31, ty = threadIdx.x >> 5;
  #pragma unroll
  for (int s = 0; s < 4; ++s)
    T[ty + 8*s][tx] = V[(mb + ty + 8*s)*512 + db + tx];
  __syncthreads();
  #pragma unroll
  for (int s = 0; s < 4; ++s)
    Vt[(db + ty + 8*s)*4096 + mb + tx] = T[tx][ty + 8*s];
}

// ---------------- fused projection GEMMs: 5 problems in one launch ----------------
// grid (128, 8): bx<64 -> query proj (x, 8192 rows); else 4 segments of 16 blocks (2048 rows)
__global__ __launch_bounds__(256) void proj_all(
    const float* __restrict__ x, const float* __restrict__ fine, const float* __restrict__ cmem,
    const unsigned short* __restrict__ WtXK, const unsigned short* __restrict__ WtK,
    const unsigned short* __restrict__ WtV,  const unsigned short* __restrict__ WtCK,
    const unsigned short* __restrict__ WtCV,
    const float* __restrict__ xkb, const float* __restrict__ kb2, const float* __restrict__ vb2,
    const float* __restrict__ ckb, const float* __restrict__ cvb,
    unsigned short* __restrict__ qry, unsigned short* __restrict__ memk,
    unsigned short* __restrict__ memv)
{
  const float* A; const unsigned short* Bt; const float* bias; unsigned short* C;
  int m0;
  int bx = blockIdx.x;
  if (bx < 64) { A = x; Bt = WtXK; bias = xkb; C = qry; m0 = bx * 128; }
  else {
    int seg = (bx - 64) >> 4;
    m0 = ((bx - 64) & 15) * 128;
    switch (seg) {
      case 0:  A = fine; Bt = WtK;  bias = kb2; C = memk;            break;
      case 1:  A = cmem; Bt = WtCK; bias = ckb; C = memk + 2048*512; break;
      case 2:  A = fine; Bt = WtV;  bias = vb2; C = memv;            break;
      default: A = cmem; Bt = WtCV; bias = cvb; C = memv + 2048*512; break;
    }
  }

  __shared__ unsigned short As[128*32];
  __shared__ unsigned short Bs[64*32];
  const int tid = threadIdx.x;
  const int w = tid >> 6, lane = tid & 63;
  const int lr = lane & 15, lg = lane >> 4;
  const int wm = w >> 1, wn = w & 1;
  const int n0 = blockIdx.y * 64;

  f32x4 acc[4][2];
  #pragma unroll
  for (int mt = 0; mt < 4; ++mt)
    #pragma unroll
    for (int nt = 0; nt < 2; ++nt) acc[mt][nt] = (f32x4){0.f,0.f,0.f,0.f};

  const int arow = tid >> 3, af4 = tid & 7;
  const int brow = tid >> 2, bc8 = tid & 3;

  for (int kb = 0; kb < 512; kb += 32) {
    #pragma unroll
    for (int s = 0; s < 4; ++s) {
      const float4 v = *(const float4*)(A + (m0 + arow + 32*s)*512 + kb + af4*4);
      unsigned long long pk = (unsigned long long)f2bf(v.x)
        | ((unsigned long long)f2bf(v.y) << 16)
        | ((unsigned long long)f2bf(v.z) << 32)
        | ((unsigned long long)f2bf(v.w) << 48);
      *(unsigned long long*)&As[(arow + 32*s)*32 + af4*4] = pk;
    }
    *(int4*)&Bs[brow*32 + bc8*8] = *(const int4*)(Bt + (n0 + brow)*512 + kb + bc8*8);
    __syncthreads();
    bf16x8 af[4], bfr[2];
    #pragma unroll
    for (int mt = 0; mt < 4; ++mt)
      af[mt] = *(const bf16x8*)&As[(wm*64 + mt*16 + lr)*32 + lg*8];
    #pragma unroll
    for (int nt = 0; nt < 2; ++nt)
      bfr[nt] = *(const bf16x8*)&Bs[(wn*32 + nt*16 + lr)*32 + lg*8];
    #pragma unroll
    for (int mt = 0; mt < 4; ++mt)
      #pragma unroll
      for (int nt = 0; nt < 2; ++nt)
        acc[mt][nt] = MFMA16(af[mt], bfr[nt], acc[mt][nt]);
    __syncthreads();
  }
  #pragma unroll
  for (int nt = 0; nt < 2; ++nt) {
    int col = n0 + wn*32 + nt*16 + lr;
    float bv = bias[col];
    #pragma unroll
    for (int mt = 0; mt < 4; ++mt) {
      #pragma unroll
      for (int j = 0; j < 4; ++j) {
        int row = m0 + wm*64 + mt*16 + lg*4 + j;
        C[row*512 + col] = f2bf(acc[mt][nt][j] + bv);
      }
    }
  }
}

// ---------------- flash attention partials, pipelined ----------------
// grid 512 = 128 q-blocks x 4 kv-chunks (chunk = bid&3 -> XCD-affine).
// 4 waves; wave w owns q rows q0..q0+15, full d=512. KVBLK=32.
// K consumed early (QK) -> refilled after barrier A; V consumed late (PV) -> refilled after barrier B.
// Both staged via global_load_lds (linear dest) with inverse-swizzled global source (rule 21).
__global__ __launch_bounds__(256, 2) void attn_kernel(
    const unsigned short* __restrict__ q,   // [8192][512] bf16
    const unsigned short* __restrict__ mk,  // [4096][512] bf16
    const unsigned short* __restrict__ vt,  // [512][4096] bf16
    unsigned short* __restrict__ opart,     // [4][8192][512] bf16, unnormalized
    float* __restrict__ mpart,              // [4][8192]
    float* __restrict__ lpart)              // [4][8192]
{
  __shared__ unsigned short Ks[32*512];     // rows 1024 B, slot^=(row&7) swizzle
  __shared__ unsigned short Vst[512*32];    // rows 64 B,  slot^=(d&3) swizzle
  __shared__ unsigned short Pb[4][16*40];   // per-wave P, rows padded to 40 elems

  const int tid = threadIdx.x;
  const int w = tid >> 6, lane = tid & 63;
  const int lr = lane & 15, lg = lane >> 4;
  const int bid = blockIdx.x;
  const int chunk = bid & 3;
  const int qb = bid >> 2;
  const int q0 = qb * 64 + w * 16;
  const int kvbase = chunk * 1024;
  const float scale = 0.04419417382415922f;  // 512^-0.5

  // Q fragments
  bf16x8 qa[16];
  {
    const bf16x8* qp = (const bf16x8*)(q + (q0 + lr) * 512);
    #pragma unroll
    for (int ks = 0; ks < 16; ++ks) qa[ks] = qp[ks*4 + lg];
  }
  f32x4 o[32];
  #pragma unroll
  for (int nt = 0; nt < 32; ++nt) o[nt] = (f32x4){0.f,0.f,0.f,0.f};
  float m[4] = {-1e30f,-1e30f,-1e30f,-1e30f};
  float l[4] = {0.f,0.f,0.f,0.f};

  #define STAGE_K(IT) do {                                                        \
    int kv0_ = kvbase + (IT) * 32;                                                \
    _Pragma("unroll")                                                             \
    for (int i_ = 0; i_ < 8; ++i_) {                                              \
      int r_ = w * 8 + i_;                                                        \
      __builtin_amdgcn_global_load_lds(                                           \
        (const __attribute__((address_space(1))) unsigned int*)                   \
          (mk + (kv0_ + r_)*512 + ((lane ^ (r_ & 7)) * 8)),                        \
        (__attribute__((address_space(3))) unsigned int*)(&Ks[r_*512]), 16, 0, 0);\
    }                                                                             \
  } while (0)

  #define STAGE_V(IT) do {                                                        \
    int kv0_ = kvbase + (IT) * 32;                                                \
    _Pragma("unroll")                                                             \
    for (int i_ = 0; i_ < 8; ++i_) {                                              \
      int d0_ = (w * 8 + i_) * 16;                                                \
      int dl_ = d0_ + (lane >> 2);                                                \
      __builtin_amdgcn_global_load_lds(                                           \
        (const __attribute__((address_space(1))) unsigned int*)                   \
          (vt + (size_t)dl_*4096 + kv0_ + (((lane & 3) ^ (dl_ & 3)) * 8)),        \
        (__attribute__((address_space(3))) unsigned int*)(&Vst[d0_*32]), 16, 0, 0);\
    }                                                                             \
  } while (0)

  STAGE_K(0);
  STAGE_V(0);
  __syncthreads();   // drains prologue staging

  for (int it = 0; it < 32; ++it) {
    // ---- QK^T: S[16 x 32] per wave, 4 independent MFMA chains ----
    f32x4 s0a = (f32x4){0.f,0.f,0.f,0.f}, s0b = (f32x4){0.f,0.f,0.f,0.f};
    f32x4 s1a = (f32x4){0.f,0.f,0.f,0.f}, s1b = (f32x4){0.f,0.f,0.f,0.f};
    __builtin_amdgcn_s_setprio(1);
    #pragma unroll
    for (int ks = 0; ks < 8; ++ks) {
      bf16x8 k0 = *(const bf16x8*)&Ks[lr*512 + (((ks*4 + lg) ^ (lr & 7)) * 8)];
      bf16x8 k1 = *(const bf16x8*)&Ks[(lr + 16)*512 + (((ks*4 + lg) ^ (lr & 7)) * 8)];
      s0a = MFMA16(qa[ks], k0, s0a);
      s1a = MFMA16(qa[ks], k1, s1a);
      bf16x8 k0b = *(const bf16x8*)&Ks[lr*512 + ((((ks + 8)*4 + lg) ^ (lr & 7)) * 8)];
      bf16x8 k1b = *(const bf16x8*)&Ks[(lr + 16)*512 + ((((ks + 8)*4 + lg) ^ (lr & 7)) * 8)];
      s0b = MFMA16(qa[ks + 8], k0b, s0b);
      s1b = MFMA16(qa[ks + 8], k1b, s1b);
    }
    __builtin_amdgcn_s_setprio(0);
    __syncthreads();  // A: all waves done reading Ks; V(it) drained

    if (it + 1 < 32) STAGE_K(it + 1);   // refill K during softmax+PV

    f32x4 s0, s1;
    float pm[4];
    #pragma unroll
    for (int j = 0; j < 4; ++j) {
      s0[j] = (s0a[j] + s0b[j]) * scale;
      s1[j] = (s1a[j] + s1b[j]) * scale;
      pm[j] = fmaxf(s0[j], s1[j]);
    }
    #pragma unroll
    for (int msk = 1; msk < 16; msk <<= 1)
      #pragma unroll
      for (int j = 0; j < 4; ++j) pm[j] = fmaxf(pm[j], __shfl_xor(pm[j], msk));

    bool ok = (pm[0] <= m[0] + 8.f) && (pm[1] <= m[1] + 8.f)
           && (pm[2] <= m[2] + 8.f) && (pm[3] <= m[3] + 8.f);
    if (!__all(ok)) {
      #pragma unroll
      for (int j = 0; j < 4; ++j) {
        float mn = fmaxf(m[j], pm[j]);
        float f = __expf(m[j] - mn);
        l[j] *= f;
        m[j] = mn;
        #pragma unroll
        for (int nt = 0; nt < 32; ++nt) o[nt][j] *= f;
      }
    }
    float rs[4];
    #pragma unroll
    for (int j = 0; j < 4; ++j) {
      float p0 = __expf(s0[j] - m[j]);
      float p1 = __expf(s1[j] - m[j]);
      rs[j] = p0 + p1;
      Pb[w][(lg*4 + j)*40 + lr] = f2bf(p0);
      Pb[w][(lg*4 + j)*40 + 16 + lr] = f2bf(p1);
    }
    #pragma unroll
    for (int msk = 1; msk < 16; msk <<= 1)
      #pragma unroll
      for (int j = 0; j < 4; ++j) rs[j] += __shfl_xor(rs[j], msk);
    #pragma unroll
    for (int j = 0; j < 4; ++j) l[j] += rs[j];

    // ---- PV: O[16 x 512] += P[16 x 32] @ V[32 x 512] ----
    bf16x8 pa = *(const bf16x8*)&Pb[w][lr*40 + lg*8];
    __builtin_amdgcn_s_setprio(1);
    #pragma unroll
    for (int nt = 0; nt < 32; ++nt) {
      int d = nt*16 + lr;
      bf16x8 vb = *(const bf16x8*)&Vst[d*32 + ((lg ^ (d & 3)) * 8)];
      o[nt] = MFMA16(pa, vb, o[nt]);
    }
    __builtin_amdgcn_s_setprio(0);
    __syncthreads();  // B: all waves done reading Vst; K(it+1) drained

    if (it + 1 < 32) STAGE_V(it + 1);   // refill V during next QK
  }

  // ---- store unnormalized partial + m/l ----
  unsigned short* ob = opart + (size_t)chunk * 8192 * 512;
  #pragma unroll
  for (int nt = 0; nt < 32; ++nt) {
    #pragma unroll
    for (int j = 0; j < 4; ++j) {
      int row = q0 + lg*4 + j;
      ob[row*512 + nt*16 + lr] = f2bf(o[nt][j]);
    }
  }
  if (lr == 0) {
    #pragma unroll
    for (int j = 0; j < 4; ++j) {
      int row = q0 + lg*4 + j;
      mpart[chunk*8192 + row] = m[j];
      lpart[chunk*8192 + row] = l[j];
    }
  }
  #undef STAGE_K
  #undef STAGE_V
}

// ---------------- combine partials ----------------
__global__ __launch_bounds__(256) void attn_combine(
    const unsigned short* __restrict__ opart, const float* __restrict__ mpart,
    const float* __restrict__ lpart, const float* __restrict__ x,
    float* __restrict__ out)
{
  int row = blockIdx.x * 2 + (threadIdx.x >> 7);
  int t = threadIdx.x & 127;
  int d0 = t * 4;
  float mc[4], lc[4];
  #pragma unroll
  for (int c = 0; c < 4; ++c) { mc[c] = mpart[c*8192 + row]; lc[c] = lpart[c*8192 + row]; }
  float M = fmaxf(fmaxf(mc[0], mc[1]), fmaxf(mc[2], mc[3]));
  float wc[4], denom = 0.f;
  #pragma unroll
  for (int c = 0; c < 4; ++c) { wc[c] = __expf(mc[c] - M); denom += wc[c] * lc[c]; }
  float inv = 1.0f / denom;
  float acc[4] = {0.f, 0.f, 0.f, 0.f};
  const unsigned short* base = opart + row*512 + d0;
  #pragma unroll
  for (int c = 0; c < 4; ++c) {
    ushort4 v = *(const ushort4*)(base + (size_t)c * 8192 * 512);
    acc[0] += wc[c]*bf2f(v.x); acc[1] += wc[c]*bf2f(v.y);
    acc[2] += wc[c]*bf2f(v.z); acc[3] += wc[c]*bf2f(v.w);
  }
  float4 xv = *(const float4*)(x + row*512 + d0);
  float4 ov;
  ov.x = xv.x + acc[0]*inv; ov.y = xv.y + acc[1]*inv;
  ov.z = xv.z + acc[2]*inv; ov.w = xv.w + acc[3]*inv;
  *(float4*)(out + row*512 + d0) = ov;
}

// ---------------- recon path (fp32 exact) ----------------
__global__ __launch_bounds__(256) void compress_pool(const float* __restrict__ fine,
    const float* __restrict__ cq, float* __restrict__ pooled)
{
  int l = blockIdx.x;
  int t = threadIdx.x;
  const float* c0 = fine + (2*l)*512;
  const float* c1 = c0 + 512;
  float q0 = cq[t], q1 = cq[t+256];
  float a0 = q0*c0[t] + q1*c0[t+256];
  float a1 = q0*c1[t] + q1*c1[t+256];
  #pragma unroll
  for (int m = 1; m < 64; m <<= 1) { a0 += __shfl_xor(a0, m); a1 += __shfl_xor(a1, m); }
  __shared__ float r0[4], r1[4];
  int w = t >> 6;
  if ((t & 63) == 0) { r0[w] = a0; r1[w] = a1; }
  __syncthreads();
  const float sc = 0.04419417382415922f;
  float g0 = (r0[0]+r0[1]+r0[2]+r0[3]) * sc;
  float g1 = (r1[0]+r1[1]+r1[2]+r1[3]) * sc;
  float mx = fmaxf(g0, g1);
  float e0 = __expf(g0-mx), e1 = __expf(g1-mx);
  float inv = 1.0f/(e0+e1);
  float w0 = e0*inv, w1 = e1*inv;
  pooled[l*512 + t]       = w0*c0[t]     + w1*c1[t];
  pooled[l*512 + t + 256] = w0*c0[t+256] + w1*c1[t+256];
}

__global__ __launch_bounds__(256) void comp_gemm(const float* __restrict__ P,
    const float* __restrict__ W, const float* __restrict__ b, float* __restrict__ out)
{
  int gid = blockIdx.x * 256 + threadIdx.x;
  int m = gid >> 9, n = gid & 511;
  const float* a = P + m * 512;
  float acc = b[n];
  #pragma unroll 8
  for (int k = 0; k < 512; ++k) acc += a[k] * W[k*512 + n];
  out[gid] = acc;
}

__global__ void zero_one(float* p) { *p = 0.f; }

__global__ __launch_bounds__(256) void interp_loss(const float* __restrict__ comp,
    const float* __restrict__ fine, float* __restrict__ loss)
{
  float acc = 0.f;
  #pragma unroll
  for (int s = 0; s < 4; ++s) {
    int e = blockIdx.x*1024 + s*256 + threadIdx.x;
    int i = e >> 9, d = e & 511;
    float src = fminf(fmaxf((i + 0.5f)*0.5f - 0.5f, 0.f), 255.f);
    int i0 = (int)src;
    int i1 = min(i0 + 1, 255);
    float fr = src - (float)i0;
    float dec = (1.f - fr)*comp[i0*512 + d] + fr*comp[i1*512 + d];
    float df = dec - fine[e];
    acc += df*df;
  }
  #pragma unroll
  for (int m = 1; m < 64; m <<= 1) acc += __shfl_xor(acc, m);
  __shared__ float r[4];
  int w = threadIdx.x >> 6;
  if ((threadIdx.x & 63) == 0) r[w] = acc;
  __syncthreads();
  if (threadIdx.x == 0)
    atomicAdd(loss, (r[0]+r[1]+r[2]+r[3]) * (1.0f/262144.0f));
}

extern "C" void kernel_launch(void* const* d_in, const int* in_sizes, int n_in,
                              void* d_out, int out_size, void* d_ws, size_t ws_size,
                              hipStream_t stream) {
  const float* x     = (const float*)d_in[0];
  const float* fine  = (const float*)d_in[1];
  const float* cmem  = (const float*)d_in[2];
  const float* cq    = (const float*)d_in[3];
  const float* compW = (const float*)d_in[4];
  const float* compb = (const float*)d_in[5];
  const float* kW    = (const float*)d_in[6];
  const float* kb_   = (const float*)d_in[7];
  const float* vW    = (const float*)d_in[8];
  const float* vb_   = (const float*)d_in[9];
  const float* xkW   = (const float*)d_in[10];
  const float* xkb   = (const float*)d_in[11];
  const float* ckW   = (const float*)d_in[12];
  const float* ckb   = (const float*)d_in[13];
  const float* cvW   = (const float*)d_in[14];
  const float* cvb   = (const float*)d_in[15];

  char* ws = (char*)d_ws;
  const size_t WT = 512*512*2;              // 512 KB per transposed weight
  unsigned short* WtK  = (unsigned short*)(ws + 0*WT);
  unsigned short* WtV  = (unsigned short*)(ws + 1*WT);
  unsigned short* WtCK = (unsigned short*)(ws + 2*WT);
  unsigned short* WtCV = (unsigned short*)(ws + 3*WT);
  unsigned short* WtXK = (unsigned short*)(ws + 4*WT);
  char* base = ws + 5*WT;
  unsigned short* memk = (unsigned short*)(base);                       // 4 MB
  unsigned short* memv = (unsigned short*)(base + (4u<<20));            // 4 MB
  unsigned short* vt   = (unsigned short*)(base + (8u<<20));            // 4 MB
  unsigned short* qry  = (unsigned short*)(base + (12u<<20));           // 8 MB
  float* pooled        = (float*)(base + (20u<<20));                    // 512 KB
  float* comp          = (float*)(base + (20u<<20) + (512u<<10));       // 512 KB
  unsigned short* opart= (unsigned short*)(base + (21u<<20));           // 32 MB
  float* mpart         = (float*)(base + (53u<<20));                    // 128 KB
  float* lpart         = (float*)(base + (53u<<20) + (128u<<10));      // 128 KB

  float* out  = (float*)d_out;
  float* loss = out + 8192*512;

  wt_transpose5<<<dim3(16,16,5), 256, 0, stream>>>(kW, vW, ckW, cvW, xkW,
                                                   WtK, WtV, WtCK, WtCV, WtXK);

  proj_all<<<dim3(128,8), 256, 0, stream>>>(x, fine, cmem,
      WtXK, WtK, WtV, WtCK, WtCV,
      xkb, kb_, vb_, ckb, cvb,
      qry, memk, memv);

  v_transpose<<<dim3(128,16), 256, 0, stream>>>(memv, vt);

  attn_kernel<<<512, 256, 0, stream>>>(qry, memk, vt, opart, mpart, lpart);
  attn_combine<<<4096, 256, 0, stream>>>(opart, mpart, lpart, x, out);

  compress_pool<<<256, 256, 0, stream>>>(fine, cq, pooled);
  comp_gemm<<<512, 256, 0, stream>>>(pooled, compW, compb, comp);
  zero_one<<<1, 1, 0, stream>>>(loss);
  interp_loss<<<256, 256, 0, stream>>>(comp, fine, loss);
}

// Round 4
// 206.367 us; speedup vs baseline: 3.0411x; 1.4040x over previous
//
#include <hip/hip_runtime.h>

typedef __attribute__((ext_vector_type(8))) short bf16x8;
typedef __attribute__((ext_vector_type(4))) float f32x4;

#define MFMA16(a,b,c) __builtin_amdgcn_mfma_f32_16x16x32_bf16((a),(b),(c),0,0,0)

__device__ __forceinline__ unsigned short f2bf(float f) {
  unsigned int u = __builtin_bit_cast(unsigned int, f);
  u = (u + 0x7FFFu + ((u >> 16) & 1u)) >> 16;
  return (unsigned short)u;
}
__device__ __forceinline__ float bf2f(unsigned short u) {
  unsigned int v = ((unsigned int)u) << 16;
  return __builtin_bit_cast(float, v);
}

// ---------------- fused weight transpose fp32 -> bf16, Wt[n][k] = W[k][n], z selects ----------------
__global__ __launch_bounds__(256) void wt_transpose5(
    const float* __restrict__ W0, const float* __restrict__ W1,
    const float* __restrict__ W2, const float* __restrict__ W3,
    const float* __restrict__ W4,
    unsigned short* __restrict__ O0, unsigned short* __restrict__ O1,
    unsigned short* __restrict__ O2, unsigned short* __restrict__ O3,
    unsigned short* __restrict__ O4)
{
  const float* W; unsigned short* Wt;
  switch (blockIdx.z) {
    case 0: W = W0; Wt = O0; break;
    case 1: W = W1; Wt = O1; break;
    case 2: W = W2; Wt = O2; break;
    case 3: W = W3; Wt = O3; break;
    default: W = W4; Wt = O4; break;
  }
  __shared__ unsigned short T[32][33];
  int kb = blockIdx.x * 32, nb = blockIdx.y * 32;
  int tx = threadIdx.x & 31, ty = threadIdx.x >> 5;
  #pragma unroll
  for (int s = 0; s < 4; ++s)
    T[ty + 8*s][tx] = f2bf(W[(kb + ty + 8*s)*512 + nb + tx]);
  __syncthreads();
  #pragma unroll
  for (int s = 0; s < 4; ++s)
    Wt[(nb + ty + 8*s)*512 + kb + tx] = T[tx][ty + 8*s];
}

// ---------------- V transpose bf16 [4096][512] -> [512][4096] ----------------
__global__ __launch_bounds__(256) void v_transpose(const unsigned short* __restrict__ V,
    unsigned short* __restrict__ Vt)
{
  __shared__ unsigned short T[32][33];
  int mb = blockIdx.x * 32, db = blockIdx.y * 32;
  int tx = threadIdx.x & 31, ty = threadIdx.x >> 5;
  #pragma unroll
  for (int s = 0; s < 4; ++s)
    T[ty + 8*s][tx] = V[(mb + ty + 8*s)*512 + db + tx];
  __syncthreads();
  #pragma unroll
  for (int s = 0; s < 4; ++s)
    Vt[(db + ty + 8*s)*4096 + mb + tx] = T[tx][ty + 8*s];
}

// ---------------- fused projection GEMMs: 5 problems in one launch ----------------
__global__ __launch_bounds__(256) void proj_all(
    const float* __restrict__ x, const float* __restrict__ fine, const float* __restrict__ cmem,
    const unsigned short* __restrict__ WtXK, const unsigned short* __restrict__ WtK,
    const unsigned short* __restrict__ WtV,  const unsigned short* __restrict__ WtCK,
    const unsigned short* __restrict__ WtCV,
    const float* __restrict__ xkb, const float* __restrict__ kb2, const float* __restrict__ vb2,
    const float* __restrict__ ckb, const float* __restrict__ cvb,
    unsigned short* __restrict__ qry, unsigned short* __restrict__ memk,
    unsigned short* __restrict__ memv)
{
  const float* A; const unsigned short* Bt; const float* bias; unsigned short* C;
  int m0;
  int bx = blockIdx.x;
  if (bx < 64) { A = x; Bt = WtXK; bias = xkb; C = qry; m0 = bx * 128; }
  else {
    int seg = (bx - 64) >> 4;
    m0 = ((bx - 64) & 15) * 128;
    switch (seg) {
      case 0:  A = fine; Bt = WtK;  bias = kb2; C = memk;            break;
      case 1:  A = cmem; Bt = WtCK; bias = ckb; C = memk + 2048*512; break;
      case 2:  A = fine; Bt = WtV;  bias = vb2; C = memv;            break;
      default: A = cmem; Bt = WtCV; bias = cvb; C = memv + 2048*512; break;
    }
  }

  __shared__ unsigned short As[128*32];
  __shared__ unsigned short Bs[64*32];
  const int tid = threadIdx.x;
  const int w = tid >> 6, lane = tid & 63;
  const int lr = lane & 15, lg = lane >> 4;
  const int wm = w >> 1, wn = w & 1;
  const int n0 = blockIdx.y * 64;

  f32x4 acc[4][2];
  #pragma unroll
  for (int mt = 0; mt < 4; ++mt)
    #pragma unroll
    for (int nt = 0; nt < 2; ++nt) acc[mt][nt] = (f32x4){0.f,0.f,0.f,0.f};

  const int arow = tid >> 3, af4 = tid & 7;
  const int brow = tid >> 2, bc8 = tid & 3;

  for (int kb = 0; kb < 512; kb += 32) {
    #pragma unroll
    for (int s = 0; s < 4; ++s) {
      const float4 v = *(const float4*)(A + (m0 + arow + 32*s)*512 + kb + af4*4);
      unsigned long long pk = (unsigned long long)f2bf(v.x)
        | ((unsigned long long)f2bf(v.y) << 16)
        | ((unsigned long long)f2bf(v.z) << 32)
        | ((unsigned long long)f2bf(v.w) << 48);
      *(unsigned long long*)&As[(arow + 32*s)*32 + af4*4] = pk;
    }
    *(int4*)&Bs[brow*32 + bc8*8] = *(const int4*)(Bt + (n0 + brow)*512 + kb + bc8*8);
    __syncthreads();
    bf16x8 af[4], bfr[2];
    #pragma unroll
    for (int mt = 0; mt < 4; ++mt)
      af[mt] = *(const bf16x8*)&As[(wm*64 + mt*16 + lr)*32 + lg*8];
    #pragma unroll
    for (int nt = 0; nt < 2; ++nt)
      bfr[nt] = *(const bf16x8*)&Bs[(wn*32 + nt*16 + lr)*32 + lg*8];
    #pragma unroll
    for (int mt = 0; mt < 4; ++mt)
      #pragma unroll
      for (int nt = 0; nt < 2; ++nt)
        acc[mt][nt] = MFMA16(af[mt], bfr[nt], acc[mt][nt]);
    __syncthreads();
  }
  #pragma unroll
  for (int nt = 0; nt < 2; ++nt) {
    int col = n0 + wn*32 + nt*16 + lr;
    float bv = bias[col];
    #pragma unroll
    for (int mt = 0; mt < 4; ++mt) {
      #pragma unroll
      for (int j = 0; j < 4; ++j) {
        int row = m0 + wm*64 + mt*16 + lg*4 + j;
        C[row*512 + col] = f2bf(acc[mt][nt][j] + bv);
      }
    }
  }
}

// ---------------- flash attention partials, pipelined, linear addressing ----------------
// grid 512 = 128 q-blocks x 4 kv-chunks (chunk = bid&3 -> XCD-affine).
// 4 waves; wave w owns q rows q0..q0+15, full d=512. KVBLK=32.
// Schedule: QK | barrier A | STAGE_K(it+1) | softmax | PV | barrier B | STAGE_V(it+1)
//   K(it+1) gl_lds drains at barrier B (window = softmax+PV);
//   V(it+1) gl_lds drains at barrier A of it+1 (window = QK).
// Layouts: Ks rows padded to 520 elems (1040 B); Vst [512][32] unpadded.
// Both are bank-uniform for b128 reads (8 lanes/quad = minimum) with pure
// base+immediate addressing — no XOR, no per-read VALU address math.
__global__ __launch_bounds__(256, 2) void attn_kernel(
    const unsigned short* __restrict__ q,   // [8192][512] bf16
    const unsigned short* __restrict__ mk,  // [4096][512] bf16
    const unsigned short* __restrict__ vt,  // [512][4096] bf16
    unsigned short* __restrict__ opart,     // [4][8192][512] bf16, unnormalized
    float* __restrict__ mpart,              // [4][8192]
    float* __restrict__ lpart)              // [4][8192]
{
  __shared__ unsigned short Ks[32*520];     // rows 1040 B (pad 16 B between gl_lds rows)
  __shared__ unsigned short Vst[512*32];    // rows 64 B, linear
  __shared__ unsigned short Pb[4][16*40];   // per-wave P, rows padded to 40 elems

  const int tid = threadIdx.x;
  const int w = tid >> 6, lane = tid & 63;
  const int lr = lane & 15, lg = lane >> 4;
  const int bid = blockIdx.x;
  const int chunk = bid & 3;
  const int qb = bid >> 2;
  const int q0 = qb * 64 + w * 16;
  const int kvbase = chunk * 1024;
  const float scale = 0.04419417382415922f;  // 512^-0.5

  // Q fragments: row q0+lr, k-slice ks*32 + lg*8
  bf16x8 qa[16];
  {
    const bf16x8* qp = (const bf16x8*)(q + (q0 + lr) * 512);
    #pragma unroll
    for (int ks = 0; ks < 16; ++ks) qa[ks] = qp[ks*4 + lg];
  }
  f32x4 o[32];
  #pragma unroll
  for (int nt = 0; nt < 32; ++nt) o[nt] = (f32x4){0.f,0.f,0.f,0.f};
  float m[4] = {-1e30f,-1e30f,-1e30f,-1e30f};
  float l[4] = {0.f,0.f,0.f,0.f};

  // K: one gl_lds per row (64 lanes x 16 B = 1024 B), linear source, padded dest rows
  #define STAGE_K(IT) do {                                                        \
    int kv0_ = kvbase + (IT) * 32;                                                \
    _Pragma("unroll")                                                             \
    for (int i_ = 0; i_ < 8; ++i_) {                                              \
      int r_ = w * 8 + i_;                                                        \
      __builtin_amdgcn_global_load_lds(                                           \
        (const __attribute__((address_space(1))) unsigned int*)                   \
          (mk + (kv0_ + r_)*512 + lane*8),                                        \
        (__attribute__((address_space(3))) unsigned int*)(&Ks[r_*520]), 16, 0, 0);\
    }                                                                             \
  } while (0)

  // V: one gl_lds covers 16 rows of 64 B; lane -> row d0+(lane>>2), col (lane&3)*8
  #define STAGE_V(IT) do {                                                        \
    int kv0_ = kvbase + (IT) * 32;                                                \
    _Pragma("unroll")                                                             \
    for (int i_ = 0; i_ < 8; ++i_) {                                              \
      int d0_ = (w * 8 + i_) * 16;                                                \
      __builtin_amdgcn_global_load_lds(                                           \
        (const __attribute__((address_space(1))) unsigned int*)                   \
          (vt + (size_t)(d0_ + (lane >> 2))*4096 + kv0_ + (lane & 3)*8),          \
        (__attribute__((address_space(3))) unsigned int*)(&Vst[d0_*32]), 16, 0, 0);\
    }                                                                             \
  } while (0)

  STAGE_K(0);
  STAGE_V(0);
  __syncthreads();   // drains prologue staging

  const unsigned short* k0p = &Ks[lr * 520];
  const unsigned short* k1p = &Ks[(lr + 16) * 520];
  const unsigned short* vsp = &Vst[lr * 32 + lg * 8];
  const unsigned short* pbp = &Pb[w][lr * 40 + lg * 8];

  for (int it = 0; it < 32; ++it) {
    // ---- QK^T: S[16 x 32] per wave; base + immediate-offset ds_reads ----
    f32x4 s0 = (f32x4){0.f,0.f,0.f,0.f}, s1 = (f32x4){0.f,0.f,0.f,0.f};
    #pragma unroll
    for (int ks = 0; ks < 16; ++ks) {
      bf16x8 kb0 = *(const bf16x8*)(k0p + ks*32 + lg*8);
      bf16x8 kb1 = *(const bf16x8*)(k1p + ks*32 + lg*8);
      s0 = MFMA16(qa[ks], kb0, s0);
      s1 = MFMA16(qa[ks], kb1, s1);
    }
    __syncthreads();  // A: all waves done reading Ks; V(it) drained

    if (it + 1 < 32) STAGE_K(it + 1);   // refill K under softmax+PV

    float pm[4];
    #pragma unroll
    for (int j = 0; j < 4; ++j) {
      s0[j] *= scale; s1[j] *= scale;
      pm[j] = fmaxf(s0[j], s1[j]);
    }
    #pragma unroll
    for (int msk = 1; msk < 16; msk <<= 1)
      #pragma unroll
      for (int j = 0; j < 4; ++j) pm[j] = fmaxf(pm[j], __shfl_xor(pm[j], msk));

    bool ok = (pm[0] <= m[0] + 8.f) && (pm[1] <= m[1] + 8.f)
           && (pm[2] <= m[2] + 8.f) && (pm[3] <= m[3] + 8.f);
    if (!__all(ok)) {
      #pragma unroll
      for (int j = 0; j < 4; ++j) {
        float mn = fmaxf(m[j], pm[j]);
        float f = __expf(m[j] - mn);
        l[j] *= f;
        m[j] = mn;
        #pragma unroll
        for (int nt = 0; nt < 32; ++nt) o[nt][j] *= f;
      }
    }
    float rs[4];
    #pragma unroll
    for (int j = 0; j < 4; ++j) {
      float p0 = __expf(s0[j] - m[j]);
      float p1 = __expf(s1[j] - m[j]);
      rs[j] = p0 + p1;
      Pb[w][(lg*4 + j)*40 + lr] = f2bf(p0);
      Pb[w][(lg*4 + j)*40 + 16 + lr] = f2bf(p1);
    }
    #pragma unroll
    for (int msk = 1; msk < 16; msk <<= 1)
      #pragma unroll
      for (int j = 0; j < 4; ++j) rs[j] += __shfl_xor(rs[j], msk);
    #pragma unroll
    for (int j = 0; j < 4; ++j) l[j] += rs[j];

    // ---- PV: O[16 x 512] += P[16 x 32] @ V[32 x 512]; base + imm offsets ----
    bf16x8 pa = *(const bf16x8*)pbp;
    #pragma unroll
    for (int nt = 0; nt < 32; ++nt) {
      bf16x8 vb = *(const bf16x8*)(vsp + nt*512);
      o[nt] = MFMA16(pa, vb, o[nt]);
    }
    __syncthreads();  // B: all waves done reading Vst; K(it+1) drained

    if (it + 1 < 32) STAGE_V(it + 1);   // refill V under next QK
  }

  // ---- store unnormalized partial + m/l ----
  unsigned short* ob = opart + (size_t)chunk * 8192 * 512;
  #pragma unroll
  for (int nt = 0; nt < 32; ++nt) {
    #pragma unroll
    for (int j = 0; j < 4; ++j) {
      int row = q0 + lg*4 + j;
      ob[row*512 + nt*16 + lr] = f2bf(o[nt][j]);
    }
  }
  if (lr == 0) {
    #pragma unroll
    for (int j = 0; j < 4; ++j) {
      int row = q0 + lg*4 + j;
      mpart[chunk*8192 + row] = m[j];
      lpart[chunk*8192 + row] = l[j];
    }
  }
  #undef STAGE_K
  #undef STAGE_V
}

// ---------------- combine partials ----------------
__global__ __launch_bounds__(256) void attn_combine(
    const unsigned short* __restrict__ opart, const float* __restrict__ mpart,
    const float* __restrict__ lpart, const float* __restrict__ x,
    float* __restrict__ out)
{
  int row = blockIdx.x * 2 + (threadIdx.x >> 7);
  int t = threadIdx.x & 127;
  int d0 = t * 4;
  float mc[4], lc[4];
  #pragma unroll
  for (int c = 0; c < 4; ++c) { mc[c] = mpart[c*8192 + row]; lc[c] = lpart[c*8192 + row]; }
  float M = fmaxf(fmaxf(mc[0], mc[1]), fmaxf(mc[2], mc[3]));
  float wc[4], denom = 0.f;
  #pragma unroll
  for (int c = 0; c < 4; ++c) { wc[c] = __expf(mc[c] - M); denom += wc[c] * lc[c]; }
  float inv = 1.0f / denom;
  float acc[4] = {0.f, 0.f, 0.f, 0.f};
  const unsigned short* base = opart + row*512 + d0;
  #pragma unroll
  for (int c = 0; c < 4; ++c) {
    ushort4 v = *(const ushort4*)(base + (size_t)c * 8192 * 512);
    acc[0] += wc[c]*bf2f(v.x); acc[1] += wc[c]*bf2f(v.y);
    acc[2] += wc[c]*bf2f(v.z); acc[3] += wc[c]*bf2f(v.w);
  }
  float4 xv = *(const float4*)(x + row*512 + d0);
  float4 ov;
  ov.x = xv.x + acc[0]*inv; ov.y = xv.y + acc[1]*inv;
  ov.z = xv.z + acc[2]*inv; ov.w = xv.w + acc[3]*inv;
  *(float4*)(out + row*512 + d0) = ov;
}

// ---------------- recon path (fp32 exact) ----------------
__global__ __launch_bounds__(256) void compress_pool(const float* __restrict__ fine,
    const float* __restrict__ cq, float* __restrict__ pooled)
{
  int l = blockIdx.x;
  int t = threadIdx.x;
  const float* c0 = fine + (2*l)*512;
  const float* c1 = c0 + 512;
  float q0 = cq[t], q1 = cq[t+256];
  float a0 = q0*c0[t] + q1*c0[t+256];
  float a1 = q0*c1[t] + q1*c1[t+256];
  #pragma unroll
  for (int m = 1; m < 64; m <<= 1) { a0 += __shfl_xor(a0, m); a1 += __shfl_xor(a1, m); }
  __shared__ float r0[4], r1[4];
  int w = t >> 6;
  if ((t & 63) == 0) { r0[w] = a0; r1[w] = a1; }
  __syncthreads();
  const float sc = 0.04419417382415922f;
  float g0 = (r0[0]+r0[1]+r0[2]+r0[3]) * sc;
  float g1 = (r1[0]+r1[1]+r1[2]+r1[3]) * sc;
  float mx = fmaxf(g0, g1);
  float e0 = __expf(g0-mx), e1 = __expf(g1-mx);
  float inv = 1.0f/(e0+e1);
  float w0 = e0*inv, w1 = e1*inv;
  pooled[l*512 + t]       = w0*c0[t]     + w1*c1[t];
  pooled[l*512 + t + 256] = w0*c0[t+256] + w1*c1[t+256];
}

__global__ __launch_bounds__(256) void comp_gemm(const float* __restrict__ P,
    const float* __restrict__ W, const float* __restrict__ b, float* __restrict__ out)
{
  int gid = blockIdx.x * 256 + threadIdx.x;
  int m = gid >> 9, n = gid & 511;
  const float* a = P + m * 512;
  float acc = b[n];
  #pragma unroll 8
  for (int k = 0; k < 512; ++k) acc += a[k] * W[k*512 + n];
  out[gid] = acc;
}

__global__ void zero_one(float* p) { *p = 0.f; }

__global__ __launch_bounds__(256) void interp_loss(const float* __restrict__ comp,
    const float* __restrict__ fine, float* __restrict__ loss)
{
  float acc = 0.f;
  #pragma unroll
  for (int s = 0; s < 4; ++s) {
    int e = blockIdx.x*1024 + s*256 + threadIdx.x;
    int i = e >> 9, d = e & 511;
    float src = fminf(fmaxf((i + 0.5f)*0.5f - 0.5f, 0.f), 255.f);
    int i0 = (int)src;
    int i1 = min(i0 + 1, 255);
    float fr = src - (float)i0;
    float dec = (1.f - fr)*comp[i0*512 + d] + fr*comp[i1*512 + d];
    float df = dec - fine[e];
    acc += df*df;
  }
  #pragma unroll
  for (int m = 1; m < 64; m <<= 1) acc += __shfl_xor(acc, m);
  __shared__ float r[4];
  int w = threadIdx.x >> 6;
  if ((threadIdx.x & 63) == 0) r[w] = acc;
  __syncthreads();
  if (threadIdx.x == 0)
    atomicAdd(loss, (r[0]+r[1]+r[2]+r[3]) * (1.0f/262144.0f));
}

extern "C" void kernel_launch(void* const* d_in, const int* in_sizes, int n_in,
                              void* d_out, int out_size, void* d_ws, size_t ws_size,
                              hipStream_t stream) {
  const float* x     = (const float*)d_in[0];
  const float* fine  = (const float*)d_in[1];
  const float* cmem  = (const float*)d_in[2];
  const float* cq    = (const float*)d_in[3];
  const float* compW = (const float*)d_in[4];
  const float* compb = (const float*)d_in[5];
  const float* kW    = (const float*)d_in[6];
  const float* kb_   = (const float*)d_in[7];
  const float* vW    = (const float*)d_in[8];
  const float* vb_   = (const float*)d_in[9];
  const float* xkW   = (const float*)d_in[10];
  const float* xkb   = (const float*)d_in[11];
  const float* ckW   = (const float*)d_in[12];
  const float* ckb   = (const float*)d_in[13];
  const float* cvW   = (const float*)d_in[14];
  const float* cvb   = (const float*)d_in[15];

  char* ws = (char*)d_ws;
  const size_t WT = 512*512*2;              // 512 KB per transposed weight
  unsigned short* WtK  = (unsigned short*)(ws + 0*WT);
  unsigned short* WtV  = (unsigned short*)(ws + 1*WT);
  unsigned short* WtCK = (unsigned short*)(ws + 2*WT);
  unsigned short* WtCV = (unsigned short*)(ws + 3*WT);
  unsigned short* WtXK = (unsigned short*)(ws + 4*WT);
  char* base = ws + 5*WT;
  unsigned short* memk = (unsigned short*)(base);                       // 4 MB
  unsigned short* memv = (unsigned short*)(base + (4u<<20));            // 4 MB
  unsigned short* vt   = (unsigned short*)(base + (8u<<20));            // 4 MB
  unsigned short* qry  = (unsigned short*)(base + (12u<<20));           // 8 MB
  float* pooled        = (float*)(base + (20u<<20));                    // 512 KB
  float* comp          = (float*)(base + (20u<<20) + (512u<<10));       // 512 KB
  unsigned short* opart= (unsigned short*)(base + (21u<<20));           // 32 MB
  float* mpart         = (float*)(base + (53u<<20));                    // 128 KB
  float* lpart         = (float*)(base + (53u<<20) + (128u<<10));      // 128 KB

  float* out  = (float*)d_out;
  float* loss = out + 8192*512;

  wt_transpose5<<<dim3(16,16,5), 256, 0, stream>>>(kW, vW, ckW, cvW, xkW,
                                                   WtK, WtV, WtCK, WtCV, WtXK);

  proj_all<<<dim3(128,8), 256, 0, stream>>>(x, fine, cmem,
      WtXK, WtK, WtV, WtCK, WtCV,
      xkb, kb_, vb_, ckb, cvb,
      qry, memk, memv);

  v_transpose<<<dim3(128,16), 256, 0, stream>>>(memv, vt);

  attn_kernel<<<512, 256, 0, stream>>>(qry, memk, vt, opart, mpart, lpart);
  attn_combine<<<4096, 256, 0, stream>>>(opart, mpart, lpart, x, out);

  compress_pool<<<256, 256, 0, stream>>>(fine, cq, pooled);
  comp_gemm<<<512, 256, 0, stream>>>(pooled, compW, compb, comp);
  zero_one<<<1, 1, 0, stream>>>(loss);
  interp_loss<<<256, 256, 0, stream>>>(comp, fine, loss);
}

// Round 6
// 189.131 us; speedup vs baseline: 3.3182x; 1.0911x over previous
//
#include <hip/hip_runtime.h>

typedef __attribute__((ext_vector_type(8))) short bf16x8;
typedef __attribute__((ext_vector_type(4))) float f32x4;
typedef __attribute__((ext_vector_type(4))) unsigned int u32x4;

#define MFMA16(a,b,c) __builtin_amdgcn_mfma_f32_16x16x32_bf16((a),(b),(c),0,0,0)

__device__ __forceinline__ unsigned short f2bf(float f) {
  unsigned int u = __builtin_bit_cast(unsigned int, f);
  u = (u + 0x7FFFu + ((u >> 16) & 1u)) >> 16;
  return (unsigned short)u;
}
__device__ __forceinline__ float bf2f(unsigned short u) {
  unsigned int v = ((unsigned int)u) << 16;
  return __builtin_bit_cast(float, v);
}
// pack two floats -> {lo: bf16(a), hi: bf16(b)} using the proven RNE helper
__device__ __forceinline__ unsigned int pack_bf16(float a, float b) {
  return ((unsigned int)f2bf(b) << 16) | (unsigned int)f2bf(a);
}

// ---------------- fused weight transpose fp32 -> bf16, Wt[n][k] = W[k][n], z selects ----------------
__global__ __launch_bounds__(256) void wt_transpose5(
    const float* __restrict__ W0, const float* __restrict__ W1,
    const float* __restrict__ W2, const float* __restrict__ W3,
    const float* __restrict__ W4,
    unsigned short* __restrict__ O0, unsigned short* __restrict__ O1,
    unsigned short* __restrict__ O2, unsigned short* __restrict__ O3,
    unsigned short* __restrict__ O4)
{
  const float* W; unsigned short* Wt;
  switch (blockIdx.z) {
    case 0: W = W0; Wt = O0; break;
    case 1: W = W1; Wt = O1; break;
    case 2: W = W2; Wt = O2; break;
    case 3: W = W3; Wt = O3; break;
    default: W = W4; Wt = O4; break;
  }
  __shared__ unsigned short T[32][33];
  int kb = blockIdx.x * 32, nb = blockIdx.y * 32;
  int tx = threadIdx.x & 31, ty = threadIdx.x >> 5;
  #pragma unroll
  for (int s = 0; s < 4; ++s)
    T[ty + 8*s][tx] = f2bf(W[(kb + ty + 8*s)*512 + nb + tx]);
  __syncthreads();
  #pragma unroll
  for (int s = 0; s < 4; ++s)
    Wt[(nb + ty + 8*s)*512 + kb + tx] = T[tx][ty + 8*s];
}

// ---------------- V transpose bf16 [4096][512] -> [512][4096] ----------------
__global__ __launch_bounds__(256) void v_transpose(const unsigned short* __restrict__ V,
    unsigned short* __restrict__ Vt)
{
  __shared__ unsigned short T[32][33];
  int mb = blockIdx.x * 32, db = blockIdx.y * 32;
  int tx = threadIdx.x & 31, ty = threadIdx.x >> 5;
  #pragma unroll
  for (int s = 0; s < 4; ++s)
    T[ty + 8*s][tx] = V[(mb + ty + 8*s)*512 + db + tx];
  __syncthreads();
  #pragma unroll
  for (int s = 0; s < 4; ++s)
    Vt[(db + ty + 8*s)*4096 + mb + tx] = T[tx][ty + 8*s];
}

// ---------------- fused projection GEMMs: 5 problems in one launch ----------------
// q-segment output pre-multiplied by 512^-0.5 (folds attn scale into projection)
__global__ __launch_bounds__(256) void proj_all(
    const float* __restrict__ x, const float* __restrict__ fine, const float* __restrict__ cmem,
    const unsigned short* __restrict__ WtXK, const unsigned short* __restrict__ WtK,
    const unsigned short* __restrict__ WtV,  const unsigned short* __restrict__ WtCK,
    const unsigned short* __restrict__ WtCV,
    const float* __restrict__ xkb, const float* __restrict__ kb2, const float* __restrict__ vb2,
    const float* __restrict__ ckb, const float* __restrict__ cvb,
    unsigned short* __restrict__ qry, unsigned short* __restrict__ memk,
    unsigned short* __restrict__ memv)
{
  const float* A; const unsigned short* Bt; const float* bias; unsigned short* C;
  int m0;
  int bx = blockIdx.x;
  if (bx < 64) { A = x; Bt = WtXK; bias = xkb; C = qry; m0 = bx * 128; }
  else {
    int seg = (bx - 64) >> 4;
    m0 = ((bx - 64) & 15) * 128;
    switch (seg) {
      case 0:  A = fine; Bt = WtK;  bias = kb2; C = memk;            break;
      case 1:  A = cmem; Bt = WtCK; bias = ckb; C = memk + 2048*512; break;
      case 2:  A = fine; Bt = WtV;  bias = vb2; C = memv;            break;
      default: A = cmem; Bt = WtCV; bias = cvb; C = memv + 2048*512; break;
    }
  }
  const float cs = (bx < 64) ? 0.04419417382415922f : 1.0f;

  __shared__ unsigned short As[128*32];
  __shared__ unsigned short Bs[64*32];
  const int tid = threadIdx.x;
  const int w = tid >> 6, lane = tid & 63;
  const int lr = lane & 15, lg = lane >> 4;
  const int wm = w >> 1, wn = w & 1;
  const int n0 = blockIdx.y * 64;

  f32x4 acc[4][2];
  #pragma unroll
  for (int mt = 0; mt < 4; ++mt)
    #pragma unroll
    for (int nt = 0; nt < 2; ++nt) acc[mt][nt] = (f32x4){0.f,0.f,0.f,0.f};

  const int arow = tid >> 3, af4 = tid & 7;
  const int brow = tid >> 2, bc8 = tid & 3;

  for (int kb = 0; kb < 512; kb += 32) {
    #pragma unroll
    for (int s = 0; s < 4; ++s) {
      const float4 v = *(const float4*)(A + (m0 + arow + 32*s)*512 + kb + af4*4);
      unsigned long long pk = (unsigned long long)f2bf(v.x)
        | ((unsigned long long)f2bf(v.y) << 16)
        | ((unsigned long long)f2bf(v.z) << 32)
        | ((unsigned long long)f2bf(v.w) << 48);
      *(unsigned long long*)&As[(arow + 32*s)*32 + af4*4] = pk;
    }
    *(int4*)&Bs[brow*32 + bc8*8] = *(const int4*)(Bt + (n0 + brow)*512 + kb + bc8*8);
    __syncthreads();
    bf16x8 af[4], bfr[2];
    #pragma unroll
    for (int mt = 0; mt < 4; ++mt)
      af[mt] = *(const bf16x8*)&As[(wm*64 + mt*16 + lr)*32 + lg*8];
    #pragma unroll
    for (int nt = 0; nt < 2; ++nt)
      bfr[nt] = *(const bf16x8*)&Bs[(wn*32 + nt*16 + lr)*32 + lg*8];
    #pragma unroll
    for (int mt = 0; mt < 4; ++mt)
      #pragma unroll
      for (int nt = 0; nt < 2; ++nt)
        acc[mt][nt] = MFMA16(af[mt], bfr[nt], acc[mt][nt]);
    __syncthreads();
  }
  #pragma unroll
  for (int nt = 0; nt < 2; ++nt) {
    int col = n0 + wn*32 + nt*16 + lr;
    float bv = bias[col];
    #pragma unroll
    for (int mt = 0; mt < 4; ++mt) {
      #pragma unroll
      for (int j = 0; j < 4; ++j) {
        int row = m0 + wm*64 + mt*16 + lg*4 + j;
        C[row*512 + col] = f2bf((acc[mt][nt][j] + bv) * cs);
      }
    }
  }
}

// ---------------- flash attention partials: swapped QK^T, in-register softmax ----------------
// grid 512 = 128 q-blocks x 4 kv-chunks (chunk = bid&3 -> XCD-affine).
// 4 waves; wave w owns q rows q0..q0+15, full d=512. KVBLK=32.
// T = mfma(K_frag, Q_frag) = S^T: lane (lr,lg) holds S[q=lr][kv = {4lg+j, 16+4lg+j}].
// Softmax per-lane; P packed via f2bf (NOT v_cvt_pk_bf16_f32 — R5's sole unverified
// primitive, suspected wrong pack semantics) and redistributed via 8 shfl into the
// PV A-fragment. No P LDS buffer. Staging schedule identical to R4 (proven).
__global__ __launch_bounds__(256, 2) void attn_kernel(
    const unsigned short* __restrict__ q,   // [8192][512] bf16, pre-scaled by 512^-0.5
    const unsigned short* __restrict__ mk,  // [4096][512] bf16
    const unsigned short* __restrict__ vt,  // [512][4096] bf16
    unsigned short* __restrict__ opart,     // [4][8192][512] bf16, unnormalized
    float* __restrict__ mpart,              // [4][8192]
    float* __restrict__ lpart)              // [4][8192]
{
  __shared__ unsigned short Ks[32*520];     // rows 1040 B (16 B pad between gl_lds rows)
  __shared__ unsigned short Vst[512*32];    // rows 64 B, linear

  const int tid = threadIdx.x;
  const int w = tid >> 6, lane = tid & 63;
  const int lr = lane & 15, lg = lane >> 4;
  const int bid = blockIdx.x;
  const int chunk = bid & 3;
  const int qb = bid >> 2;
  const int q0 = qb * 64 + w * 16;
  const int kvbase = chunk * 1024;

  // Q fragments: row q0+lr, k-slice ks*32 + lg*8 (serve as MFMA B-operand)
  bf16x8 qa[16];
  {
    const bf16x8* qp = (const bf16x8*)(q + (q0 + lr) * 512);
    #pragma unroll
    for (int ks = 0; ks < 16; ++ks) qa[ks] = qp[ks*4 + lg];
  }
  f32x4 o[32];
  #pragma unroll
  for (int nt = 0; nt < 32; ++nt) o[nt] = (f32x4){0.f,0.f,0.f,0.f};
  float m = -1e30f, l = 0.f;   // per-lane, for q-row q0 + lr (replicated across lg)

  const int srcA = lr + ((lg & 1) << 5);   // redistribution source lanes
  const int srcB = srcA + 16;
  const bool hi = (lg >> 1) != 0;

  #define STAGE_K(IT) do {                                                        \
    int kv0_ = kvbase + (IT) * 32;                                                \
    _Pragma("unroll")                                                             \
    for (int i_ = 0; i_ < 8; ++i_) {                                              \
      int r_ = w * 8 + i_;                                                        \
      __builtin_amdgcn_global_load_lds(                                           \
        (const __attribute__((address_space(1))) unsigned int*)                   \
          (mk + (kv0_ + r_)*512 + lane*8),                                        \
        (__attribute__((address_space(3))) unsigned int*)(&Ks[r_*520]), 16, 0, 0);\
    }                                                                             \
  } while (0)

  #define STAGE_V(IT) do {                                                        \
    int kv0_ = kvbase + (IT) * 32;                                                \
    _Pragma("unroll")                                                             \
    for (int i_ = 0; i_ < 8; ++i_) {                                              \
      int d0_ = (w * 8 + i_) * 16;                                                \
      __builtin_amdgcn_global_load_lds(                                           \
        (const __attribute__((address_space(1))) unsigned int*)                   \
          (vt + (size_t)(d0_ + (lane >> 2))*4096 + kv0_ + (lane & 3)*8),          \
        (__attribute__((address_space(3))) unsigned int*)(&Vst[d0_*32]), 16, 0, 0);\
    }                                                                             \
  } while (0)

  STAGE_K(0);
  STAGE_V(0);
  __syncthreads();   // drains prologue staging

  const unsigned short* k0p = &Ks[lr * 520];          // K rows kv0..kv0+15 (A-frag)
  const unsigned short* k1p = &Ks[(lr + 16) * 520];   // K rows kv0+16..31
  const unsigned short* vsp = &Vst[lr * 32 + lg * 8];

  for (int it = 0; it < 32; ++it) {
    // ---- QK^T swapped: T = K·Q^T, 4 independent chains ----
    f32x4 t0a = (f32x4){0.f,0.f,0.f,0.f}, t0b = (f32x4){0.f,0.f,0.f,0.f};
    f32x4 t1a = (f32x4){0.f,0.f,0.f,0.f}, t1b = (f32x4){0.f,0.f,0.f,0.f};
    #pragma unroll
    for (int ks = 0; ks < 8; ++ks) {
      bf16x8 kb0 = *(const bf16x8*)(k0p + ks*32 + lg*8);
      bf16x8 kb1 = *(const bf16x8*)(k1p + ks*32 + lg*8);
      t0a = MFMA16(kb0, qa[ks], t0a);
      t1a = MFMA16(kb1, qa[ks], t1a);
      bf16x8 kb0b = *(const bf16x8*)(k0p + (ks+8)*32 + lg*8);
      bf16x8 kb1b = *(const bf16x8*)(k1p + (ks+8)*32 + lg*8);
      t0b = MFMA16(kb0b, qa[ks+8], t0b);
      t1b = MFMA16(kb1b, qa[ks+8], t1b);
    }
    __syncthreads();  // A: all waves done reading Ks; V(it) drained

    if (it + 1 < 32) STAGE_K(it + 1);   // refill K under softmax+PV

    float t0[4], t1[4];
    #pragma unroll
    for (int j = 0; j < 4; ++j) { t0[j] = t0a[j] + t0b[j]; t1[j] = t1a[j] + t1b[j]; }

    // ---- per-lane softmax for q = q0 + lr ----
    float pm = fmaxf(fmaxf(fmaxf(t0[0], t0[1]), fmaxf(t0[2], t0[3])),
                     fmaxf(fmaxf(t1[0], t1[1]), fmaxf(t1[2], t1[3])));
    pm = fmaxf(pm, __shfl_xor(pm, 16));
    pm = fmaxf(pm, __shfl_xor(pm, 32));

    if (!__all(pm <= m + 8.f)) {
      float mn = fmaxf(m, pm);
      float fl = __expf(m - mn);
      l *= fl;
      m = mn;
      float f0 = __shfl(fl, 4*lg + 0);
      float f1 = __shfl(fl, 4*lg + 1);
      float f2 = __shfl(fl, 4*lg + 2);
      float f3 = __shfl(fl, 4*lg + 3);
      #pragma unroll
      for (int nt = 0; nt < 32; ++nt) {
        o[nt][0] *= f0; o[nt][1] *= f1; o[nt][2] *= f2; o[nt][3] *= f3;
      }
    }

    float p0[4], p1[4];
    #pragma unroll
    for (int j = 0; j < 4; ++j) {
      p0[j] = __expf(t0[j] - m);
      p1[j] = __expf(t1[j] - m);
    }
    float rs = ((p0[0] + p0[1]) + (p0[2] + p0[3]))
             + ((p1[0] + p1[1]) + (p1[2] + p1[3]));
    rs += __shfl_xor(rs, 16);
    rs += __shfl_xor(rs, 32);
    l += rs;

    // ---- pack P to bf16 pairs (f2bf, proven RNE) and redistribute into PV A-frag ----
    unsigned int u0 = pack_bf16(p0[0], p0[1]);   // kv 4lg+0 (lo), 4lg+1 (hi)
    unsigned int u1 = pack_bf16(p0[2], p0[3]);   // kv 4lg+2,3
    unsigned int u2 = pack_bf16(p1[0], p1[1]);   // kv 16+4lg+0,1
    unsigned int u3 = pack_bf16(p1[2], p1[3]);   // kv 16+4lg+2,3
    unsigned int a0 = __shfl(u0, srcA), b0 = __shfl(u2, srcA);
    unsigned int a1 = __shfl(u1, srcA), b1 = __shfl(u3, srcA);
    unsigned int a2 = __shfl(u0, srcB), b2 = __shfl(u2, srcB);
    unsigned int a3 = __shfl(u1, srcB), b3 = __shfl(u3, srcB);
    u32x4 pr;
    pr[0] = hi ? b0 : a0;   // kv 8lg+0,1
    pr[1] = hi ? b1 : a1;   // kv 8lg+2,3
    pr[2] = hi ? b2 : a2;   // kv 8lg+4,5
    pr[3] = hi ? b3 : a3;   // kv 8lg+6,7
    bf16x8 pa = __builtin_bit_cast(bf16x8, pr);

    // ---- PV: O[16 x 512] += P[16 x 32] @ V[32 x 512] ----
    #pragma unroll
    for (int nt = 0; nt < 32; ++nt) {
      bf16x8 vb = *(const bf16x8*)(vsp + nt*512);
      o[nt] = MFMA16(pa, vb, o[nt]);
    }
    __syncthreads();  // B: all waves done reading Vst; K(it+1) drained

    if (it + 1 < 32) STAGE_V(it + 1);   // refill V under next QK
  }

  // ---- store unnormalized partial + m/l ----
  unsigned short* ob = opart + (size_t)chunk * 8192 * 512;
  #pragma unroll
  for (int nt = 0; nt < 32; ++nt) {
    #pragma unroll
    for (int j = 0; j < 4; ++j) {
      int row = q0 + lg*4 + j;
      ob[row*512 + nt*16 + lr] = f2bf(o[nt][j]);
    }
  }
  if (lane < 16) {
    mpart[chunk*8192 + q0 + lane] = m;
    lpart[chunk*8192 + q0 + lane] = l;
  }
  #undef STAGE_K
  #undef STAGE_V
}

// ---------------- combine partials ----------------
__global__ __launch_bounds__(256) void attn_combine(
    const unsigned short* __restrict__ opart, const float* __restrict__ mpart,
    const float* __restrict__ lpart, const float* __restrict__ x,
    float* __restrict__ out)
{
  int row = blockIdx.x * 2 + (threadIdx.x >> 7);
  int t = threadIdx.x & 127;
  int d0 = t * 4;
  float mc[4], lc[4];
  #pragma unroll
  for (int c = 0; c < 4; ++c) { mc[c] = mpart[c*8192 + row]; lc[c] = lpart[c*8192 + row]; }
  float M = fmaxf(fmaxf(mc[0], mc[1]), fmaxf(mc[2], mc[3]));
  float wc[4], denom = 0.f;
  #pragma unroll
  for (int c = 0; c < 4; ++c) { wc[c] = __expf(mc[c] - M); denom += wc[c] * lc[c]; }
  float inv = 1.0f / denom;
  float acc[4] = {0.f, 0.f, 0.f, 0.f};
  const unsigned short* base = opart + row*512 + d0;
  #pragma unroll
  for (int c = 0; c < 4; ++c) {
    ushort4 v = *(const ushort4*)(base + (size_t)c * 8192 * 512);
    acc[0] += wc[c]*bf2f(v.x); acc[1] += wc[c]*bf2f(v.y);
    acc[2] += wc[c]*bf2f(v.z); acc[3] += wc[c]*bf2f(v.w);
  }
  float4 xv = *(const float4*)(x + row*512 + d0);
  float4 ov;
  ov.x = xv.x + acc[0]*inv; ov.y = xv.y + acc[1]*inv;
  ov.z = xv.z + acc[2]*inv; ov.w = xv.w + acc[3]*inv;
  *(float4*)(out + row*512 + d0) = ov;
}

// ---------------- recon path (fp32 exact) ----------------
__global__ __launch_bounds__(256) void compress_pool(const float* __restrict__ fine,
    const float* __restrict__ cq, float* __restrict__ pooled)
{
  int l = blockIdx.x;
  int t = threadIdx.x;
  const float* c0 = fine + (2*l)*512;
  const float* c1 = c0 + 512;
  float q0 = cq[t], q1 = cq[t+256];
  float a0 = q0*c0[t] + q1*c0[t+256];
  float a1 = q0*c1[t] + q1*c1[t+256];
  #pragma unroll
  for (int m = 1; m < 64; m <<= 1) { a0 += __shfl_xor(a0, m); a1 += __shfl_xor(a1, m); }
  __shared__ float r0[4], r1[4];
  int w = t >> 6;
  if ((t & 63) == 0) { r0[w] = a0; r1[w] = a1; }
  __syncthreads();
  const float sc = 0.04419417382415922f;
  float g0 = (r0[0]+r0[1]+r0[2]+r0[3]) * sc;
  float g1 = (r1[0]+r1[1]+r1[2]+r1[3]) * sc;
  float mx = fmaxf(g0, g1);
  float e0 = __expf(g0-mx), e1 = __expf(g1-mx);
  float inv = 1.0f/(e0+e1);
  float w0 = e0*inv, w1 = e1*inv;
  pooled[l*512 + t]       = w0*c0[t]     + w1*c1[t];
  pooled[l*512 + t + 256] = w0*c0[t+256] + w1*c1[t+256];
}

__global__ __launch_bounds__(256) void comp_gemm(const float* __restrict__ P,
    const float* __restrict__ W, const float* __restrict__ b, float* __restrict__ out)
{
  int gid = blockIdx.x * 256 + threadIdx.x;
  int m = gid >> 9, n = gid & 511;
  const float* a = P + m * 512;
  float acc = b[n];
  #pragma unroll 8
  for (int k = 0; k < 512; ++k) acc += a[k] * W[k*512 + n];
  out[gid] = acc;
}

__global__ void zero_one(float* p) { *p = 0.f; }

__global__ __launch_bounds__(256) void interp_loss(const float* __restrict__ comp,
    const float* __restrict__ fine, float* __restrict__ loss)
{
  float acc = 0.f;
  #pragma unroll
  for (int s = 0; s < 4; ++s) {
    int e = blockIdx.x*1024 + s*256 + threadIdx.x;
    int i = e >> 9, d = e & 511;
    float src = fminf(fmaxf((i + 0.5f)*0.5f - 0.5f, 0.f), 255.f);
    int i0 = (int)src;
    int i1 = min(i0 + 1, 255);
    float fr = src - (float)i0;
    float dec = (1.f - fr)*comp[i0*512 + d] + fr*comp[i1*512 + d];
    float df = dec - fine[e];
    acc += df*df;
  }
  #pragma unroll
  for (int m = 1; m < 64; m <<= 1) acc += __shfl_xor(acc, m);
  __shared__ float r[4];
  int w = threadIdx.x >> 6;
  if ((threadIdx.x & 63) == 0) r[w] = acc;
  __syncthreads();
  if (threadIdx.x == 0)
    atomicAdd(loss, (r[0]+r[1]+r[2]+r[3]) * (1.0f/262144.0f));
}

extern "C" void kernel_launch(void* const* d_in, const int* in_sizes, int n_in,
                              void* d_out, int out_size, void* d_ws, size_t ws_size,
                              hipStream_t stream) {
  const float* x     = (const float*)d_in[0];
  const float* fine  = (const float*)d_in[1];
  const float* cmem  = (const float*)d_in[2];
  const float* cq    = (const float*)d_in[3];
  const float* compW = (const float*)d_in[4];
  const float* compb = (const float*)d_in[5];
  const float* kW    = (const float*)d_in[6];
  const float* kb_   = (const float*)d_in[7];
  const float* vW    = (const float*)d_in[8];
  const float* vb_   = (const float*)d_in[9];
  const float* xkW   = (const float*)d_in[10];
  const float* xkb   = (const float*)d_in[11];
  const float* ckW   = (const float*)d_in[12];
  const float* ckb   = (const float*)d_in[13];
  const float* cvW   = (const float*)d_in[14];
  const float* cvb   = (const float*)d_in[15];

  char* ws = (char*)d_ws;
  const size_t WT = 512*512*2;              // 512 KB per transposed weight
  unsigned short* WtK  = (unsigned short*)(ws + 0*WT);
  unsigned short* WtV  = (unsigned short*)(ws + 1*WT);
  unsigned short* WtCK = (unsigned short*)(ws + 2*WT);
  unsigned short* WtCV = (unsigned short*)(ws + 3*WT);
  unsigned short* WtXK = (unsigned short*)(ws + 4*WT);
  char* base = ws + 5*WT;
  unsigned short* memk = (unsigned short*)(base);                       // 4 MB
  unsigned short* memv = (unsigned short*)(base + (4u<<20));            // 4 MB
  unsigned short* vt   = (unsigned short*)(base + (8u<<20));            // 4 MB
  unsigned short* qry  = (unsigned short*)(base + (12u<<20));           // 8 MB
  float* pooled        = (float*)(base + (20u<<20));                    // 512 KB
  float* comp          = (float*)(base + (20u<<20) + (512u<<10));       // 512 KB
  unsigned short* opart= (unsigned short*)(base + (21u<<20));           // 32 MB
  float* mpart         = (float*)(base + (53u<<20));                    // 128 KB
  float* lpart         = (float*)(base + (53u<<20) + (128u<<10));      // 128 KB

  float* out  = (float*)d_out;
  float* loss = out + 8192*512;

  wt_transpose5<<<dim3(16,16,5), 256, 0, stream>>>(kW, vW, ckW, cvW, xkW,
                                                   WtK, WtV, WtCK, WtCV, WtXK);

  proj_all<<<dim3(128,8), 256, 0, stream>>>(x, fine, cmem,
      WtXK, WtK, WtV, WtCK, WtCV,
      xkb, kb_, vb_, ckb, cvb,
      qry, memk, memv);

  v_transpose<<<dim3(128,16), 256, 0, stream>>>(memv, vt);

  attn_kernel<<<512, 256, 0, stream>>>(qry, memk, vt, opart, mpart, lpart);
  attn_combine<<<4096, 256, 0, stream>>>(opart, mpart, lpart, x, out);

  compress_pool<<<256, 256, 0, stream>>>(fine, cq, pooled);
  comp_gemm<<<512, 256, 0, stream>>>(pooled, compW, compb, comp);
  zero_one<<<1, 1, 0, stream>>>(loss);
  interp_loss<<<256, 256, 0, stream>>>(comp, fine, loss);
}